// Round 18
// baseline (3096.761 us; speedup 1.0000x reference)
//
#include <hip/hip_runtime.h>
#include <hip/hip_bf16.h>
#include <math.h>

// ---------------------------------------------------------------------------
// KVPLM Star Encoder: 12 layers, H=768, NH=12, F=3072, B=16, S=512.
// Round 18: attn occupancy fix — z 4->8, ONE q-tile/wave (VGPR ~60), LDS
// 23 KB, launch_bounds(256,6) -> 6 blocks/CU = 24 waves/CU, grid 1536 =
// exactly one round. R17's staged K/V kept (cooperative, VMEM-cheap).
// GEMMs/LN frozen at R16/R17 (gemm_n64 + fast GELU + fused V-transpose).
// ---------------------------------------------------------------------------

#define L_   12
#define H_   768
#define NH_  12
#define DH_  64
#define F_   3072
#define B_   16
#define S_   512
#define NTOK (B_ * S_)   // 8192
#define QKVN 2304

typedef __attribute__((ext_vector_type(8))) __bf16 bf16x8;
typedef __attribute__((ext_vector_type(4))) __bf16 bf16x4;
typedef __attribute__((ext_vector_type(4))) float  f32x4;

static __device__ __forceinline__ f32x4 mfma16(bf16x8 a, bf16x8 b, f32x4 c) {
  return __builtin_amdgcn_mfma_f32_16x16x32_bf16(a, b, c, 0, 0, 0);
}

static __device__ __forceinline__ void load_lds16(const void* g, void* l) {
  __builtin_amdgcn_global_load_lds(
      (const __attribute__((address_space(1))) void*)g,
      (__attribute__((address_space(3))) void*)l, 16, 0, 0);
}

// tanh-approx GELU (max dev vs exact ~4e-4, under bf16 rounding)
static __device__ __forceinline__ float gelu_fast(float v) {
  const float u = 1.5957691216057308f * v * (1.0f + 0.044715f * v * v);
  return v / (1.0f + __expf(-u));
}

// ---------------------------------------------------------------------------
// Weight transpose+convert: in fp32 [Z][R][C] -> out bf16 [Z (stride outZ)][C][R]
// ---------------------------------------------------------------------------
__global__ __launch_bounds__(256) void transpose_k(const float* __restrict__ in,
                                                   __bf16* __restrict__ out,
                                                   int R, int C, size_t outZ) {
  __shared__ float t[32][33];
  const int z = blockIdx.z;
  const float* inz = in + (size_t)z * R * C;
  __bf16* outz = out + (size_t)z * outZ;
  const int c0 = blockIdx.x * 32, r0 = blockIdx.y * 32;
  const int tx = threadIdx.x, ty = threadIdx.y;
#pragma unroll
  for (int i = 0; i < 32; i += 8)
    t[ty + i][tx] = inz[(size_t)(r0 + ty + i) * C + c0 + tx];
  __syncthreads();
#pragma unroll
  for (int i = 0; i < 32; i += 8)
    outz[(size_t)(c0 + ty + i) * R + r0 + tx] = (__bf16)t[tx][ty + i];
}

__global__ __launch_bounds__(256) void concat_bias(const float* __restrict__ bq,
                                                   const float* __restrict__ bk,
                                                   const float* __restrict__ bv,
                                                   float* __restrict__ o) {
  const int i = blockIdx.x * 256 + threadIdx.x;
  if (i >= L_ * QKVN) return;
  const int l = i / QKVN, j = i - l * QKVN;
  float v;
  if (j < H_) v = bq[l * H_ + j];
  else if (j < 2 * H_) v = bk[l * H_ + j - H_];
  else v = bv[l * H_ + j - 2 * H_];
  o[i] = v;
}

// ---------------------------------------------------------------------------
// gemm_n64 (R13 local optimum): 2-phase 128x64 GEMM, BK=64, LDS 48 KiB dbuf
// -> 3 blocks/CU. T2 st_16x32 swizzle + T3-minimal schedule. VT=1 (QKV):
// cols >= 2H write transposed into vtp[(b*NH+h)*64+d][s] (bf16x4 per frag).
// ---------------------------------------------------------------------------
template <int EPI, int OUTBF, int VT>
__global__ __launch_bounds__(256, 3) void gemm_n64(const __bf16* __restrict__ A,
                                                   const __bf16* __restrict__ Bt,
                                                   const float* __restrict__ bias,
                                                   float* __restrict__ Cf,
                                                   __bf16* __restrict__ Cb,
                                                   __bf16* __restrict__ vtp,
                                                   int M, int N, int K, int Ntiles) {
  alignas(16) __shared__ __bf16 lds[24576];  // [buf2][A 8192 | B 4096] el
  const int tid = threadIdx.x, wid = tid >> 6, lane = tid & 63;
  int bid = blockIdx.x;
  const int nwg = gridDim.x;
  if ((nwg & 7) == 0) bid = (bid & 7) * (nwg >> 3) + (bid >> 3);  // XCD swizzle
  const int bm = (bid / Ntiles) << 7, bn = (bid % Ntiles) << 6;
  const int nt = K >> 6;

  const __bf16* pA[4];
  const __bf16* pB[2];
#pragma unroll
  for (int j = 0; j < 4; ++j) {
    const int E = (j << 11) + tid * 8;
    const int Ep = E ^ (((E >> 8) & 1) << 4);
    const int r = ((Ep >> 10) << 4) | ((Ep >> 5) & 15);
    const int c = (((Ep >> 9) & 1) << 5) | (Ep & 31);
    pA[j] = A + (size_t)(bm + r) * K + c;
    if (j < 2) pB[j] = Bt + (size_t)(bn + r) * K + c;  // r < 64 for E < 4096
  }

  auto stage = [&](int t, int buf) {
    __bf16* base = &lds[buf * 12288 + (wid << 9)];
    const size_t off = (size_t)(t << 6);
#pragma unroll
    for (int j = 0; j < 4; ++j) load_lds16(pA[j] + off, base + (j << 11));
#pragma unroll
    for (int j = 0; j < 2; ++j) load_lds16(pB[j] + off, base + 8192 + (j << 11));
  };

  const int frow = lane & 15, fk = (lane >> 4) << 3;
  const int swzb = (frow * 32 + fk) ^ (((frow >> 3) & 1) << 4);
  const int mh = wid >> 1, nq = wid & 1;  // wave tile 64x32

  f32x4 acc[4][2] = {};

  stage(0, 0);
  asm volatile("s_waitcnt vmcnt(0)" ::: "memory");
  __builtin_amdgcn_s_barrier();

  for (int t = 0; t < nt; ++t) {
    const int buf = t & 1;
    if (t + 1 < nt) stage(t + 1, buf ^ 1);   // issue BEFORE ds_read+MFMA
    const __bf16* LA = &lds[buf * 12288 + (mh << 12)];
    const __bf16* LB = &lds[buf * 12288 + 8192 + (nq << 11)];
    bf16x8 a[4][2], b[2][2];
#pragma unroll
    for (int mi = 0; mi < 4; ++mi)
#pragma unroll
      for (int ks = 0; ks < 2; ++ks)
        a[mi][ks] = *(const bf16x8*)&LA[mi * 1024 + ks * 512 + swzb];
#pragma unroll
    for (int ni = 0; ni < 2; ++ni)
#pragma unroll
      for (int ks = 0; ks < 2; ++ks)
        b[ni][ks] = *(const bf16x8*)&LB[ni * 1024 + ks * 512 + swzb];
    asm volatile("s_waitcnt lgkmcnt(0)" ::: "memory");
    __builtin_amdgcn_s_setprio(1);
#pragma unroll
    for (int mi = 0; mi < 4; ++mi)
#pragma unroll
      for (int ni = 0; ni < 2; ++ni)
#pragma unroll
        for (int ks = 0; ks < 2; ++ks)
          acc[mi][ni] = mfma16(a[mi][ks], b[ni][ks], acc[mi][ni]);
    __builtin_amdgcn_s_setprio(0);
    asm volatile("s_waitcnt vmcnt(0)" ::: "memory");  // next tile staged
    __builtin_amdgcn_s_barrier();
  }

  // epilogue: C/D layout col=lane&15, row=(lane>>4)*4+r  [m89 verified]
  const int r0 = (lane >> 4) << 2, c0 = lane & 15;
  const int wrow = bm + (mh << 6), wcol = bn + (nq << 5);
#pragma unroll
  for (int ni = 0; ni < 2; ++ni) {
    const int col = wcol + (ni << 4) + c0;
    const float bv = bias[col];
    if (VT && (wcol + (ni << 4)) >= 2 * H_) {
      const int hh = (col - 2 * H_) >> 6, dd = (col - 2 * H_) & 63;
#pragma unroll
      for (int mi = 0; mi < 4; ++mi) {
        const int row = wrow + (mi << 4) + r0;
        bf16x4 pv;
#pragma unroll
        for (int r = 0; r < 4; ++r) pv[r] = (__bf16)(acc[mi][ni][r] + bv);
        const int bb2 = row >> 9, ss = row & 511;
        *(bf16x4*)&vtp[((size_t)(bb2 * NH_ + hh) * DH_ + dd) * S_ + ss] = pv;
      }
    } else {
#pragma unroll
      for (int mi = 0; mi < 4; ++mi) {
        const int row = wrow + (mi << 4) + r0;
#pragma unroll
        for (int r = 0; r < 4; ++r) {
          float v = acc[mi][ni][r] + bv;
          if (EPI == 1) v = gelu_fast(v);
          if (OUTBF)
            Cb[(size_t)(row + r) * N + col] = (__bf16)v;
          else
            Cf[(size_t)(row + r) * N + col] = v;
        }
      }
    }
  }
}

// ---------------------------------------------------------------------------
// Flash attention, swapped QK^T, ONE q-tile/wave, K/V staged per block in LDS
// (T2 swizzle). LDS 23 KB; launch_bounds(256,6) -> 6 blocks/CU; grid
// (NH,B,8) = 1536 = exactly one round @ 6/CU (24 waves/CU).
// ---------------------------------------------------------------------------
__global__ __launch_bounds__(256, 6) void attn_kernel(const __bf16* __restrict__ qkv,
                                                      const __bf16* __restrict__ vt,
                                                      const int* __restrict__ amask,
                                                      __bf16* __restrict__ ctx) {
  __shared__ float extm[S_];                      // 2 KB
  alignas(16) __shared__ __bf16 Kl[2][2048];      // 8 KB [buf][rg2|cg2|16|32]
  alignas(16) __shared__ __bf16 Vl[2][2048];      // 8 KB [buf][rg4|16|32]
  __shared__ __bf16 Pl[4][16][40];                // 5 KB
  const int h = blockIdx.x, b = blockIdx.y, z = blockIdx.z;
  const int tid = threadIdx.x, wid = tid >> 6, lane = tid & 63;
  const size_t rowb = (size_t)b * S_ * QKVN + (size_t)h * DH_;
  const __bf16* vbase = vt + ((size_t)(b * NH_ + h) * DH_) * S_;

  for (int i = tid; i < S_; i += 256)
    extm[i] = (1.0f - (float)amask[b * S_ + i]) * -10000.0f;

  // per-thread staging source coords (inverse st_16x32 swizzle, rule #21)
  const int E = tid * 8;
  const int Ep = E ^ (((E >> 8) & 1) << 4);
  const int krow = ((Ep >> 10) << 4) | ((Ep >> 5) & 15);   // key within tile
  const int kcol = (((Ep >> 9) & 1) << 5) | (Ep & 31);     // d
  const __bf16* ksrc = qkv + rowb + (size_t)krow * QKVN + H_ + kcol;
  const int vd = ((Ep >> 9) << 4) | ((Ep >> 5) & 15);      // d
  const int vs = Ep & 31;                                  // s within tile
  const __bf16* vsrc = vbase + (size_t)vd * S_ + vs;

  auto stageKV = [&](int kt, int buf) {
    load_lds16(ksrc + (size_t)(kt * 32) * QKVN, &Kl[buf][E]);
    load_lds16(vsrc + kt * 32, &Vl[buf][E]);
  };

  const int c0 = lane & 15, g4 = lane >> 4;
  const int swzb = (c0 * 32 + (g4 << 3)) ^ (((c0 >> 3) & 1) << 4);
  const int qt = z * 4 + wid;        // 0..31, exactly one per wave
  bf16x8 qf0, qf1;
  {
    const __bf16* qrow = qkv + rowb + (size_t)(qt * 16 + c0) * QKVN + (g4 << 3);
    qf0 = *(const bf16x8*)qrow;
    qf1 = *(const bf16x8*)(qrow + 32);
  }
  f32x4 oacc[4] = {};
  float mrow = -1e30f, lsum = 0.f;

  stageKV(0, 0);
  asm volatile("s_waitcnt vmcnt(0)" ::: "memory");
  __syncthreads();   // extm + KV tile 0 ready

#pragma unroll
  for (int kt = 0; kt < 16; ++kt) {
    const int buf = kt & 1;
    if (kt + 1 < 16) stageKV(kt + 1, buf ^ 1);   // issue BEFORE compute
    bf16x8 kf[2][2], vf[4];
#pragma unroll
    for (int f = 0; f < 2; ++f)
#pragma unroll
      for (int half = 0; half < 2; ++half)
        kf[f][half] = *(const bf16x8*)&Kl[buf][f * 1024 + half * 512 + swzb];
#pragma unroll
    for (int dt = 0; dt < 4; ++dt)
      vf[dt] = *(const bf16x8*)&Vl[buf][dt * 512 + swzb];
    asm volatile("s_waitcnt lgkmcnt(0)" ::: "memory");
    f32x4 sc[2];
    __builtin_amdgcn_s_setprio(1);
#pragma unroll
    for (int f = 0; f < 2; ++f) {
      f32x4 z2 = {};
      z2 = mfma16(kf[f][0], qf0, z2);   // SWAPPED: C[m=key][n=q]
      z2 = mfma16(kf[f][1], qf1, z2);
#pragma unroll
      for (int r = 0; r < 4; ++r)
        sc[f][r] = z2[r] * 0.125f + extm[kt * 32 + f * 16 + (g4 << 2) + r];
    }
    __builtin_amdgcn_s_setprio(0);
    float mx = fmaxf(fmaxf(fmaxf(sc[0][0], sc[0][1]), fmaxf(sc[0][2], sc[0][3])),
                     fmaxf(fmaxf(sc[1][0], sc[1][1]), fmaxf(sc[1][2], sc[1][3])));
    mx = fmaxf(mx, __shfl_xor(mx, 16, 64));
    mx = fmaxf(mx, __shfl_xor(mx, 32, 64));
    const float mn = fmaxf(mrow, mx);
    const float al = __expf(mrow - mn);
    mrow = mn;
    float rs = 0.f;
    bf16x4 p0, p1;
#pragma unroll
    for (int r = 0; r < 4; ++r) {
      const float pa0 = __expf(sc[0][r] - mn);
      const float pa1 = __expf(sc[1][r] - mn);
      p0[r] = (__bf16)pa0;
      p1[r] = (__bf16)pa1;
      rs += pa0 + pa1;
    }
    rs += __shfl_xor(rs, 16, 64);
    rs += __shfl_xor(rs, 32, 64);
    lsum = lsum * al + rs;
    *(bf16x4*)&Pl[wid][c0][(g4 << 2)] = p0;
    *(bf16x4*)&Pl[wid][c0][16 + (g4 << 2)] = p1;
    float alr[4];
#pragma unroll
    for (int r = 0; r < 4; ++r)
      alr[r] = __shfl(al, (lane & 48) | ((g4 << 2) + r), 64);
#pragma unroll
    for (int dt = 0; dt < 4; ++dt)
#pragma unroll
      for (int r = 0; r < 4; ++r) oacc[dt][r] *= alr[r];
    const bf16x8 pa = *(const bf16x8*)&Pl[wid][c0][g4 << 3];
    __builtin_amdgcn_s_setprio(1);
#pragma unroll
    for (int dt = 0; dt < 4; ++dt)
      oacc[dt] = mfma16(pa, vf[dt], oacc[dt]);
    __builtin_amdgcn_s_setprio(0);
    asm volatile("s_waitcnt vmcnt(0)" ::: "memory");  // next KV tile staged
    __builtin_amdgcn_s_barrier();
  }
  float inv[4];
#pragma unroll
  for (int r = 0; r < 4; ++r)
    inv[r] = 1.0f / __shfl(lsum, (lane & 48) | ((g4 << 2) + r), 64);
#pragma unroll
  for (int dt = 0; dt < 4; ++dt)
#pragma unroll
    for (int r = 0; r < 4; ++r)
      ctx[(size_t)b * S_ * H_ + (size_t)h * DH_ +
          (size_t)(qt * 16 + (g4 << 2) + r) * H_ + dt * 16 + c0] =
          (__bf16)(oacc[dt][r] * inv[r]);
}

// ---------------------------------------------------------------------------
// Residual add + LayerNorm, ONE WAVE PER TOKEN. t is bf16 (half traffic).
// ---------------------------------------------------------------------------
__global__ __launch_bounds__(256) void addln_kernel(float* __restrict__ x,
                                                    const __bf16* __restrict__ t,
                                                    const float* __restrict__ g,
                                                    const float* __restrict__ bb,
                                                    __bf16* __restrict__ xb) {
  const int tok = blockIdx.x * 4 + (threadIdx.x >> 6);
  const int lane = threadIdx.x & 63;
  float* xr = x + (size_t)tok * H_;
  const __bf16* tr = t + (size_t)tok * H_;
  f32x4 v[3];
  float s = 0.f, s2 = 0.f;
#pragma unroll
  for (int i = 0; i < 3; ++i) {
    const int off = lane * 4 + i * 256;
    f32x4 a = *(const f32x4*)&xr[off];
    bf16x4 tb = *(const bf16x4*)&tr[off];
#pragma unroll
    for (int r = 0; r < 4; ++r) {
      v[i][r] = a[r] + (float)tb[r];
      s += v[i][r];
      s2 += v[i][r] * v[i][r];
    }
  }
#pragma unroll
  for (int o = 32; o > 0; o >>= 1) {
    s += __shfl_xor(s, o, 64);
    s2 += __shfl_xor(s2, o, 64);
  }
  const float mean = s * (1.0f / 768.0f);
  const float var = s2 * (1.0f / 768.0f) - mean * mean;
  const float rstd = rsqrtf(var + 1e-12f);
  __bf16* xbr = xb + (size_t)tok * H_;
#pragma unroll
  for (int i = 0; i < 3; ++i) {
    const int off = lane * 4 + i * 256;
    f32x4 gv = *(const f32x4*)&g[off];
    f32x4 bv = *(const f32x4*)&bb[off];
    f32x4 y;
    bf16x4 yb;
#pragma unroll
    for (int r = 0; r < 4; ++r) {
      y[r] = (v[i][r] - mean) * rstd * gv[r] + bv[r];
      yb[r] = (__bf16)y[r];
    }
    *(f32x4*)&xr[off] = y;
    *(bf16x4*)&xbr[off] = yb;
  }
}

// ---------------------------------------------------------------------------
// Embedding (word/star select + pos + type) + LN.
// ---------------------------------------------------------------------------
__global__ __launch_bounds__(256) void embed_kernel(
    const int* __restrict__ ids, const int* __restrict__ tt,
    const float* __restrict__ we, const float* __restrict__ se,
    const float* __restrict__ pe, const float* __restrict__ te,
    const float* __restrict__ g, const float* __restrict__ bb,
    float* __restrict__ x, __bf16* __restrict__ xb) {
  const int tok = blockIdx.x, tid = threadIdx.x;
  const int sp = tok & (S_ - 1);
  const int id = ids[tok];
  const float* e = (id >= 30700) ? se + (size_t)(id - 30700) * H_
                                 : we + (size_t)id * H_;
  const float* pr = pe + (size_t)sp * H_;
  const float* ty = te + (size_t)tt[tok] * H_;
  float v0 = e[tid] + pr[tid] + ty[tid];
  float v1 = e[tid + 256] + pr[tid + 256] + ty[tid + 256];
  float v2 = e[tid + 512] + pr[tid + 512] + ty[tid + 512];
  float s = v0 + v1 + v2;
  float s2 = v0 * v0 + v1 * v1 + v2 * v2;
  __shared__ float red1[4], red2[4];
#pragma unroll
  for (int o = 32; o > 0; o >>= 1) {
    s += __shfl_xor(s, o, 64);
    s2 += __shfl_xor(s2, o, 64);
  }
  if ((tid & 63) == 0) { red1[tid >> 6] = s; red2[tid >> 6] = s2; }
  __syncthreads();
  s = red1[0] + red1[1] + red1[2] + red1[3];
  s2 = red2[0] + red2[1] + red2[2] + red2[3];
  const float mean = s * (1.0f / 768.0f);
  const float var = s2 * (1.0f / 768.0f) - mean * mean;
  const float rstd = rsqrtf(var + 1e-12f);
  float* xr = x + (size_t)tok * H_;
  __bf16* xbr = xb + (size_t)tok * H_;
  const float y0 = (v0 - mean) * rstd * g[tid] + bb[tid];
  const float y1 = (v1 - mean) * rstd * g[tid + 256] + bb[tid + 256];
  const float y2 = (v2 - mean) * rstd * g[tid + 512] + bb[tid + 512];
  xr[tid] = y0; xr[tid + 256] = y1; xr[tid + 512] = y2;
  xbr[tid] = (__bf16)y0; xbr[tid + 256] = (__bf16)y1; xbr[tid + 512] = (__bf16)y2;
}

// ---------------------------------------------------------------------------
// Pooler: pooled[b] = tanh(x[b,0,:] @ poolW + pool_b).
// ---------------------------------------------------------------------------
__global__ __launch_bounds__(256) void pool_kernel(const float* __restrict__ x,
                                                   const __bf16* __restrict__ wT,
                                                   const float* __restrict__ pb,
                                                   float* __restrict__ out) {
  const int b = blockIdx.x, tid = threadIdx.x;
  __shared__ float xr[H_];
  for (int i = tid; i < H_; i += 256) xr[i] = x[(size_t)b * S_ * H_ + i];
  __syncthreads();
  for (int n = tid; n < H_; n += 256) {
    const __bf16* w = wT + (size_t)n * H_;
    float acc = 0.f;
    for (int k = 0; k < H_; ++k) acc += xr[k] * (float)w[k];
    out[(size_t)b * H_ + n] = tanhf(acc + pb[n]);
  }
}

// ---------------------------------------------------------------------------
extern "C" void kernel_launch(void* const* d_in, const int* in_sizes, int n_in,
                              void* d_out, int out_size, void* d_ws,
                              size_t ws_size, hipStream_t stream) {
  (void)in_sizes; (void)n_in; (void)out_size;
  const int* ids = (const int*)d_in[0];
  const int* am = (const int*)d_in[1];
  const int* tt = (const int*)d_in[2];
  const float* we = (const float*)d_in[3];
  const float* se = (const float*)d_in[4];
  const float* pe = (const float*)d_in[5];
  const float* te = (const float*)d_in[6];
  const float* eg = (const float*)d_in[7];
  const float* ebb = (const float*)d_in[8];
  const float* Wq = (const float*)d_in[9];
  const float* bq = (const float*)d_in[10];
  const float* Wk = (const float*)d_in[11];
  const float* bk = (const float*)d_in[12];
  const float* Wv = (const float*)d_in[13];
  const float* bv = (const float*)d_in[14];
  const float* Wo = (const float*)d_in[15];
  const float* bo = (const float*)d_in[16];
  const float* g1 = (const float*)d_in[17];
  const float* b1 = (const float*)d_in[18];
  const float* Wi = (const float*)d_in[19];
  const float* bi = (const float*)d_in[20];
  const float* Wf = (const float*)d_in[21];
  const float* bf_ = (const float*)d_in[22];
  const float* g2 = (const float*)d_in[23];
  const float* b2 = (const float*)d_in[24];
  const float* pw = (const float*)d_in[25];
  const float* pb = (const float*)d_in[26];

  const size_t WQKV = (size_t)L_ * QKVN * H_;
  const size_t WSQ = (size_t)L_ * H_ * H_;
  const size_t WSF = (size_t)L_ * H_ * F_;
  const size_t MN = (size_t)NTOK * H_;
  __bf16* wqkv = (__bf16*)d_ws;
  __bf16* wTo_ = wqkv + WQKV;
  __bf16* wTi_ = wTo_ + WSQ;
  __bf16* wTf_ = wTi_ + WSF;
  __bf16* wTp_ = wTf_ + WSF;
  __bf16* xb = wTp_ + (size_t)H_ * H_;
  __bf16* qkvb = xb + MN;
  __bf16* cb = qkvb + (size_t)NTOK * QKVN;
  __bf16* mid = cb + MN;
  __bf16* vtb = mid + (size_t)NTOK * F_;
  __bf16* t0b = vtb + MN;               // AO/FF2 bf16 output (12.6 MB)
  float* bqkv = (float*)(t0b + MN);
  const size_t needed = (size_t)((char*)(bqkv + (size_t)L_ * QKVN) - (char*)d_ws);
  if (ws_size < needed) return;  // insufficient scratch: visible failure

  float* x = (float*)d_out;
  float* pooled = x + MN;

  const dim3 tb(32, 8);
  const size_t zq = (size_t)QKVN * H_;
  transpose_k<<<dim3(24, 24, 12), tb, 0, stream>>>(Wq, wqkv, H_, H_, zq);
  transpose_k<<<dim3(24, 24, 12), tb, 0, stream>>>(Wk, wqkv + (size_t)H_ * H_, H_, H_, zq);
  transpose_k<<<dim3(24, 24, 12), tb, 0, stream>>>(Wv, wqkv + 2 * (size_t)H_ * H_, H_, H_, zq);
  transpose_k<<<dim3(24, 24, 12), tb, 0, stream>>>(Wo, wTo_, H_, H_, (size_t)H_ * H_);
  transpose_k<<<dim3(96, 24, 12), tb, 0, stream>>>(Wi, wTi_, H_, F_, (size_t)H_ * F_);
  transpose_k<<<dim3(24, 96, 12), tb, 0, stream>>>(Wf, wTf_, F_, H_, (size_t)H_ * F_);
  transpose_k<<<dim3(24, 24, 1), tb, 0, stream>>>(pw, wTp_, H_, H_, (size_t)H_ * H_);
  concat_bias<<<(L_ * QKVN + 255) / 256, 256, 0, stream>>>(bq, bk, bv, bqkv);

  embed_kernel<<<NTOK, 256, 0, stream>>>(ids, tt, we, se, pe, te, eg, ebb, x, xb);

  for (int l = 0; l < L_; ++l) {
    // fused QKV (V written transposed in-epilogue): 2304 blocks
    gemm_n64<0, 1, 1><<<(NTOK / 128) * (QKVN / 64), 256, 0, stream>>>(
        xb, wqkv + (size_t)l * QKVN * H_, bqkv + (size_t)l * QKVN,
        nullptr, qkvb, vtb, NTOK, QKVN, H_, QKVN / 64);

    attn_kernel<<<dim3(NH_, B_, 8), 256, 0, stream>>>(qkvb, vtb, am, cb);

    // attn-out: 768 blocks; bf16 output
    gemm_n64<0, 1, 0><<<(NTOK / 128) * (H_ / 64), 256, 0, stream>>>(
        cb, wTo_ + (size_t)l * H_ * H_, bo + l * H_, nullptr, t0b, nullptr,
        NTOK, H_, H_, H_ / 64);
    addln_kernel<<<NTOK / 4, 256, 0, stream>>>(x, t0b, g1 + l * H_, b1 + l * H_, xb);

    // FF1: 3072 blocks (fast GELU epilogue)
    gemm_n64<1, 1, 0><<<(NTOK / 128) * (F_ / 64), 256, 0, stream>>>(
        xb, wTi_ + (size_t)l * H_ * F_, bi + l * F_, nullptr, mid, nullptr,
        NTOK, F_, H_, F_ / 64);
    // FF2: 768 blocks; bf16 output
    gemm_n64<0, 1, 0><<<(NTOK / 128) * (H_ / 64), 256, 0, stream>>>(
        mid, wTf_ + (size_t)l * F_ * H_, bf_ + l * H_, nullptr, t0b, nullptr,
        NTOK, H_, F_, H_ / 64);
    addln_kernel<<<NTOK / 4, 256, 0, stream>>>(x, t0b, g2 + l * H_, b2 + l * H_, xb);
  }

  pool_kernel<<<B_, 256, 0, stream>>>(x, wTp_, pb, pooled);
}

// Round 19
// 3039.027 us; speedup vs baseline: 1.0190x; 1.0190x over previous
//
#include <hip/hip_runtime.h>
#include <hip/hip_bf16.h>
#include <math.h>

// ---------------------------------------------------------------------------
// KVPLM Star Encoder: 12 layers, H=768, NH=12, F=3072, B=16, S=512.
// Round 19: revert attn to R17 local optimum (2 q-tiles/wave, 3 blk/CU —
// R18's 6/CU regressed; occupancy is not attn's lever). NEW: attn grid
// linearized 768 with XCD-chunked swizzle (T1) so the 4 z-siblings of each
// (b,h) — which stage identical K/V — share one XCD L2.
// GEMMs/LN frozen at R16/R17 (gemm_n64, fast GELU, fused V-transpose).
// ---------------------------------------------------------------------------

#define L_   12
#define H_   768
#define NH_  12
#define DH_  64
#define F_   3072
#define B_   16
#define S_   512
#define NTOK (B_ * S_)   // 8192
#define QKVN 2304

typedef __attribute__((ext_vector_type(8))) __bf16 bf16x8;
typedef __attribute__((ext_vector_type(4))) __bf16 bf16x4;
typedef __attribute__((ext_vector_type(4))) float  f32x4;

static __device__ __forceinline__ f32x4 mfma16(bf16x8 a, bf16x8 b, f32x4 c) {
  return __builtin_amdgcn_mfma_f32_16x16x32_bf16(a, b, c, 0, 0, 0);
}

static __device__ __forceinline__ void load_lds16(const void* g, void* l) {
  __builtin_amdgcn_global_load_lds(
      (const __attribute__((address_space(1))) void*)g,
      (__attribute__((address_space(3))) void*)l, 16, 0, 0);
}

// tanh-approx GELU (max dev vs exact ~4e-4, under bf16 rounding)
static __device__ __forceinline__ float gelu_fast(float v) {
  const float u = 1.5957691216057308f * v * (1.0f + 0.044715f * v * v);
  return v / (1.0f + __expf(-u));
}

// ---------------------------------------------------------------------------
// Weight transpose+convert: in fp32 [Z][R][C] -> out bf16 [Z (stride outZ)][C][R]
// ---------------------------------------------------------------------------
__global__ __launch_bounds__(256) void transpose_k(const float* __restrict__ in,
                                                   __bf16* __restrict__ out,
                                                   int R, int C, size_t outZ) {
  __shared__ float t[32][33];
  const int z = blockIdx.z;
  const float* inz = in + (size_t)z * R * C;
  __bf16* outz = out + (size_t)z * outZ;
  const int c0 = blockIdx.x * 32, r0 = blockIdx.y * 32;
  const int tx = threadIdx.x, ty = threadIdx.y;
#pragma unroll
  for (int i = 0; i < 32; i += 8)
    t[ty + i][tx] = inz[(size_t)(r0 + ty + i) * C + c0 + tx];
  __syncthreads();
#pragma unroll
  for (int i = 0; i < 32; i += 8)
    outz[(size_t)(c0 + ty + i) * R + r0 + tx] = (__bf16)t[tx][ty + i];
}

__global__ __launch_bounds__(256) void concat_bias(const float* __restrict__ bq,
                                                   const float* __restrict__ bk,
                                                   const float* __restrict__ bv,
                                                   float* __restrict__ o) {
  const int i = blockIdx.x * 256 + threadIdx.x;
  if (i >= L_ * QKVN) return;
  const int l = i / QKVN, j = i - l * QKVN;
  float v;
  if (j < H_) v = bq[l * H_ + j];
  else if (j < 2 * H_) v = bk[l * H_ + j - H_];
  else v = bv[l * H_ + j - 2 * H_];
  o[i] = v;
}

// ---------------------------------------------------------------------------
// gemm_n64 (R13 local optimum): 2-phase 128x64 GEMM, BK=64, LDS 48 KiB dbuf
// -> 3 blocks/CU. T2 st_16x32 swizzle + T3-minimal schedule. VT=1 (QKV):
// cols >= 2H write transposed into vtp[(b*NH+h)*64+d][s] (bf16x4 per frag).
// ---------------------------------------------------------------------------
template <int EPI, int OUTBF, int VT>
__global__ __launch_bounds__(256, 3) void gemm_n64(const __bf16* __restrict__ A,
                                                   const __bf16* __restrict__ Bt,
                                                   const float* __restrict__ bias,
                                                   float* __restrict__ Cf,
                                                   __bf16* __restrict__ Cb,
                                                   __bf16* __restrict__ vtp,
                                                   int M, int N, int K, int Ntiles) {
  alignas(16) __shared__ __bf16 lds[24576];  // [buf2][A 8192 | B 4096] el
  const int tid = threadIdx.x, wid = tid >> 6, lane = tid & 63;
  int bid = blockIdx.x;
  const int nwg = gridDim.x;
  if ((nwg & 7) == 0) bid = (bid & 7) * (nwg >> 3) + (bid >> 3);  // XCD swizzle
  const int bm = (bid / Ntiles) << 7, bn = (bid % Ntiles) << 6;
  const int nt = K >> 6;

  const __bf16* pA[4];
  const __bf16* pB[2];
#pragma unroll
  for (int j = 0; j < 4; ++j) {
    const int E = (j << 11) + tid * 8;
    const int Ep = E ^ (((E >> 8) & 1) << 4);
    const int r = ((Ep >> 10) << 4) | ((Ep >> 5) & 15);
    const int c = (((Ep >> 9) & 1) << 5) | (Ep & 31);
    pA[j] = A + (size_t)(bm + r) * K + c;
    if (j < 2) pB[j] = Bt + (size_t)(bn + r) * K + c;  // r < 64 for E < 4096
  }

  auto stage = [&](int t, int buf) {
    __bf16* base = &lds[buf * 12288 + (wid << 9)];
    const size_t off = (size_t)(t << 6);
#pragma unroll
    for (int j = 0; j < 4; ++j) load_lds16(pA[j] + off, base + (j << 11));
#pragma unroll
    for (int j = 0; j < 2; ++j) load_lds16(pB[j] + off, base + 8192 + (j << 11));
  };

  const int frow = lane & 15, fk = (lane >> 4) << 3;
  const int swzb = (frow * 32 + fk) ^ (((frow >> 3) & 1) << 4);
  const int mh = wid >> 1, nq = wid & 1;  // wave tile 64x32

  f32x4 acc[4][2] = {};

  stage(0, 0);
  asm volatile("s_waitcnt vmcnt(0)" ::: "memory");
  __builtin_amdgcn_s_barrier();

  for (int t = 0; t < nt; ++t) {
    const int buf = t & 1;
    if (t + 1 < nt) stage(t + 1, buf ^ 1);   // issue BEFORE ds_read+MFMA
    const __bf16* LA = &lds[buf * 12288 + (mh << 12)];
    const __bf16* LB = &lds[buf * 12288 + 8192 + (nq << 11)];
    bf16x8 a[4][2], b[2][2];
#pragma unroll
    for (int mi = 0; mi < 4; ++mi)
#pragma unroll
      for (int ks = 0; ks < 2; ++ks)
        a[mi][ks] = *(const bf16x8*)&LA[mi * 1024 + ks * 512 + swzb];
#pragma unroll
    for (int ni = 0; ni < 2; ++ni)
#pragma unroll
      for (int ks = 0; ks < 2; ++ks)
        b[ni][ks] = *(const bf16x8*)&LB[ni * 1024 + ks * 512 + swzb];
    asm volatile("s_waitcnt lgkmcnt(0)" ::: "memory");
    __builtin_amdgcn_s_setprio(1);
#pragma unroll
    for (int mi = 0; mi < 4; ++mi)
#pragma unroll
      for (int ni = 0; ni < 2; ++ni)
#pragma unroll
        for (int ks = 0; ks < 2; ++ks)
          acc[mi][ni] = mfma16(a[mi][ks], b[ni][ks], acc[mi][ni]);
    __builtin_amdgcn_s_setprio(0);
    asm volatile("s_waitcnt vmcnt(0)" ::: "memory");  // next tile staged
    __builtin_amdgcn_s_barrier();
  }

  // epilogue: C/D layout col=lane&15, row=(lane>>4)*4+r  [m89 verified]
  const int r0 = (lane >> 4) << 2, c0 = lane & 15;
  const int wrow = bm + (mh << 6), wcol = bn + (nq << 5);
#pragma unroll
  for (int ni = 0; ni < 2; ++ni) {
    const int col = wcol + (ni << 4) + c0;
    const float bv = bias[col];
    if (VT && (wcol + (ni << 4)) >= 2 * H_) {
      const int hh = (col - 2 * H_) >> 6, dd = (col - 2 * H_) & 63;
#pragma unroll
      for (int mi = 0; mi < 4; ++mi) {
        const int row = wrow + (mi << 4) + r0;
        bf16x4 pv;
#pragma unroll
        for (int r = 0; r < 4; ++r) pv[r] = (__bf16)(acc[mi][ni][r] + bv);
        const int bb2 = row >> 9, ss = row & 511;
        *(bf16x4*)&vtp[((size_t)(bb2 * NH_ + hh) * DH_ + dd) * S_ + ss] = pv;
      }
    } else {
#pragma unroll
      for (int mi = 0; mi < 4; ++mi) {
        const int row = wrow + (mi << 4) + r0;
#pragma unroll
        for (int r = 0; r < 4; ++r) {
          float v = acc[mi][ni][r] + bv;
          if (EPI == 1) v = gelu_fast(v);
          if (OUTBF)
            Cb[(size_t)(row + r) * N + col] = (__bf16)v;
          else
            Cf[(size_t)(row + r) * N + col] = v;
        }
      }
    }
  }
}

// ---------------------------------------------------------------------------
// Flash attention (R17 local optimum), swapped QK^T, TWO q-tiles/wave, K/V
// staged once per block in LDS (T2 swizzle). Grid 768 LINEAR with XCD-chunk
// swizzle: swz=(bid&7)*96+(bid>>3); z-siblings of one (b,h) share an XCD L2.
// ---------------------------------------------------------------------------
__global__ __launch_bounds__(256, 3) void attn_kernel(const __bf16* __restrict__ qkv,
                                                      const __bf16* __restrict__ vt,
                                                      const int* __restrict__ amask,
                                                      __bf16* __restrict__ ctx) {
  __shared__ float extm[S_];                      // 2 KB
  alignas(16) __shared__ __bf16 Kl[2][2048];      // 8 KB [buf][rg2|cg2|16|32]
  alignas(16) __shared__ __bf16 Vl[2][2048];      // 8 KB [buf][rg4|16|32]
  __shared__ __bf16 Pl[4][2][16][40];             // 10 KB
  // XCD-chunked decode: each XCD owns 96 consecutive logical ids
  const int swz = ((int)blockIdx.x & 7) * 96 + ((int)blockIdx.x >> 3);
  const int z = swz & 3;
  const int hb = swz >> 2;
  const int h = hb % NH_, b = hb / NH_;
  const int tid = threadIdx.x, wid = tid >> 6, lane = tid & 63;
  const size_t rowb = (size_t)b * S_ * QKVN + (size_t)h * DH_;
  const __bf16* vbase = vt + ((size_t)(b * NH_ + h) * DH_) * S_;

  for (int i = tid; i < S_; i += 256)
    extm[i] = (1.0f - (float)amask[b * S_ + i]) * -10000.0f;

  // per-thread staging source coords (inverse st_16x32 swizzle, rule #21)
  const int E = tid * 8;
  const int Ep = E ^ (((E >> 8) & 1) << 4);
  const int krow = ((Ep >> 10) << 4) | ((Ep >> 5) & 15);   // key within tile
  const int kcol = (((Ep >> 9) & 1) << 5) | (Ep & 31);     // d
  const __bf16* ksrc = qkv + rowb + (size_t)krow * QKVN + H_ + kcol;
  const int vd = ((Ep >> 9) << 4) | ((Ep >> 5) & 15);      // d
  const int vs = Ep & 31;                                  // s within tile
  const __bf16* vsrc = vbase + (size_t)vd * S_ + vs;

  auto stageKV = [&](int kt, int buf) {
    load_lds16(ksrc + (size_t)(kt * 32) * QKVN, &Kl[buf][E]);
    load_lds16(vsrc + kt * 32, &Vl[buf][E]);
  };

  const int c0 = lane & 15, g4 = lane >> 4;
  const int swzb = (c0 * 32 + (g4 << 3)) ^ (((c0 >> 3) & 1) << 4);
  const int qt0 = z * 8 + wid * 2;   // this wave's two q-tiles
  bf16x8 qf[2][2];
#pragma unroll
  for (int qi = 0; qi < 2; ++qi) {
    const __bf16* qrow = qkv + rowb +
        (size_t)((qt0 + qi) * 16 + c0) * QKVN + (g4 << 3);
    qf[qi][0] = *(const bf16x8*)qrow;
    qf[qi][1] = *(const bf16x8*)(qrow + 32);
  }
  f32x4 oacc[2][4] = {};
  float mrow[2] = {-1e30f, -1e30f}, lsum[2] = {0.f, 0.f};

  stageKV(0, 0);
  asm volatile("s_waitcnt vmcnt(0)" ::: "memory");
  __syncthreads();   // extm + KV tile 0 ready

#pragma unroll
  for (int kt = 0; kt < 16; ++kt) {
    const int buf = kt & 1;
    if (kt + 1 < 16) stageKV(kt + 1, buf ^ 1);   // issue BEFORE compute
    bf16x8 kf[2][2], vf[4];
#pragma unroll
    for (int f = 0; f < 2; ++f)
#pragma unroll
      for (int half = 0; half < 2; ++half)
        kf[f][half] = *(const bf16x8*)&Kl[buf][f * 1024 + half * 512 + swzb];
#pragma unroll
    for (int dt = 0; dt < 4; ++dt)
      vf[dt] = *(const bf16x8*)&Vl[buf][dt * 512 + swzb];
    asm volatile("s_waitcnt lgkmcnt(0)" ::: "memory");
#pragma unroll
    for (int qi = 0; qi < 2; ++qi) {
      f32x4 sc[2];
      __builtin_amdgcn_s_setprio(1);
#pragma unroll
      for (int f = 0; f < 2; ++f) {
        f32x4 z2 = {};
        z2 = mfma16(kf[f][0], qf[qi][0], z2);   // SWAPPED: C[m=key][n=q]
        z2 = mfma16(kf[f][1], qf[qi][1], z2);
#pragma unroll
        for (int r = 0; r < 4; ++r)
          sc[f][r] = z2[r] * 0.125f + extm[kt * 32 + f * 16 + (g4 << 2) + r];
      }
      __builtin_amdgcn_s_setprio(0);
      float mx = fmaxf(fmaxf(fmaxf(sc[0][0], sc[0][1]), fmaxf(sc[0][2], sc[0][3])),
                       fmaxf(fmaxf(sc[1][0], sc[1][1]), fmaxf(sc[1][2], sc[1][3])));
      mx = fmaxf(mx, __shfl_xor(mx, 16, 64));
      mx = fmaxf(mx, __shfl_xor(mx, 32, 64));
      const float mn = fmaxf(mrow[qi], mx);
      const float al = __expf(mrow[qi] - mn);
      mrow[qi] = mn;
      float rs = 0.f;
      bf16x4 p0, p1;
#pragma unroll
      for (int r = 0; r < 4; ++r) {
        const float pa0 = __expf(sc[0][r] - mn);
        const float pa1 = __expf(sc[1][r] - mn);
        p0[r] = (__bf16)pa0;
        p1[r] = (__bf16)pa1;
        rs += pa0 + pa1;
      }
      rs += __shfl_xor(rs, 16, 64);
      rs += __shfl_xor(rs, 32, 64);
      lsum[qi] = lsum[qi] * al + rs;
      *(bf16x4*)&Pl[wid][qi][c0][(g4 << 2)] = p0;
      *(bf16x4*)&Pl[wid][qi][c0][16 + (g4 << 2)] = p1;
      float alr[4];
#pragma unroll
      for (int r = 0; r < 4; ++r)
        alr[r] = __shfl(al, (lane & 48) | ((g4 << 2) + r), 64);
#pragma unroll
      for (int dt = 0; dt < 4; ++dt)
#pragma unroll
        for (int r = 0; r < 4; ++r) oacc[qi][dt][r] *= alr[r];
      const bf16x8 pa = *(const bf16x8*)&Pl[wid][qi][c0][g4 << 3];
      __builtin_amdgcn_s_setprio(1);
#pragma unroll
      for (int dt = 0; dt < 4; ++dt)
        oacc[qi][dt] = mfma16(pa, vf[dt], oacc[qi][dt]);
      __builtin_amdgcn_s_setprio(0);
    }
    asm volatile("s_waitcnt vmcnt(0)" ::: "memory");  // next KV tile staged
    __builtin_amdgcn_s_barrier();
  }
#pragma unroll
  for (int qi = 0; qi < 2; ++qi) {
    float inv[4];
#pragma unroll
    for (int r = 0; r < 4; ++r)
      inv[r] = 1.0f / __shfl(lsum[qi], (lane & 48) | ((g4 << 2) + r), 64);
#pragma unroll
    for (int dt = 0; dt < 4; ++dt)
#pragma unroll
      for (int r = 0; r < 4; ++r)
        ctx[(size_t)b * S_ * H_ + (size_t)h * DH_ +
            (size_t)((qt0 + qi) * 16 + (g4 << 2) + r) * H_ + dt * 16 + c0] =
            (__bf16)(oacc[qi][dt][r] * inv[r]);
  }
}

// ---------------------------------------------------------------------------
// Residual add + LayerNorm, ONE WAVE PER TOKEN. t is bf16 (half traffic).
// ---------------------------------------------------------------------------
__global__ __launch_bounds__(256) void addln_kernel(float* __restrict__ x,
                                                    const __bf16* __restrict__ t,
                                                    const float* __restrict__ g,
                                                    const float* __restrict__ bb,
                                                    __bf16* __restrict__ xb) {
  const int tok = blockIdx.x * 4 + (threadIdx.x >> 6);
  const int lane = threadIdx.x & 63;
  float* xr = x + (size_t)tok * H_;
  const __bf16* tr = t + (size_t)tok * H_;
  f32x4 v[3];
  float s = 0.f, s2 = 0.f;
#pragma unroll
  for (int i = 0; i < 3; ++i) {
    const int off = lane * 4 + i * 256;
    f32x4 a = *(const f32x4*)&xr[off];
    bf16x4 tb = *(const bf16x4*)&tr[off];
#pragma unroll
    for (int r = 0; r < 4; ++r) {
      v[i][r] = a[r] + (float)tb[r];
      s += v[i][r];
      s2 += v[i][r] * v[i][r];
    }
  }
#pragma unroll
  for (int o = 32; o > 0; o >>= 1) {
    s += __shfl_xor(s, o, 64);
    s2 += __shfl_xor(s2, o, 64);
  }
  const float mean = s * (1.0f / 768.0f);
  const float var = s2 * (1.0f / 768.0f) - mean * mean;
  const float rstd = rsqrtf(var + 1e-12f);
  __bf16* xbr = xb + (size_t)tok * H_;
#pragma unroll
  for (int i = 0; i < 3; ++i) {
    const int off = lane * 4 + i * 256;
    f32x4 gv = *(const f32x4*)&g[off];
    f32x4 bv = *(const f32x4*)&bb[off];
    f32x4 y;
    bf16x4 yb;
#pragma unroll
    for (int r = 0; r < 4; ++r) {
      y[r] = (v[i][r] - mean) * rstd * gv[r] + bv[r];
      yb[r] = (__bf16)y[r];
    }
    *(f32x4*)&xr[off] = y;
    *(bf16x4*)&xbr[off] = yb;
  }
}

// ---------------------------------------------------------------------------
// Embedding (word/star select + pos + type) + LN.
// ---------------------------------------------------------------------------
__global__ __launch_bounds__(256) void embed_kernel(
    const int* __restrict__ ids, const int* __restrict__ tt,
    const float* __restrict__ we, const float* __restrict__ se,
    const float* __restrict__ pe, const float* __restrict__ te,
    const float* __restrict__ g, const float* __restrict__ bb,
    float* __restrict__ x, __bf16* __restrict__ xb) {
  const int tok = blockIdx.x, tid = threadIdx.x;
  const int sp = tok & (S_ - 1);
  const int id = ids[tok];
  const float* e = (id >= 30700) ? se + (size_t)(id - 30700) * H_
                                 : we + (size_t)id * H_;
  const float* pr = pe + (size_t)sp * H_;
  const float* ty = te + (size_t)tt[tok] * H_;
  float v0 = e[tid] + pr[tid] + ty[tid];
  float v1 = e[tid + 256] + pr[tid + 256] + ty[tid + 256];
  float v2 = e[tid + 512] + pr[tid + 512] + ty[tid + 512];
  float s = v0 + v1 + v2;
  float s2 = v0 * v0 + v1 * v1 + v2 * v2;
  __shared__ float red1[4], red2[4];
#pragma unroll
  for (int o = 32; o > 0; o >>= 1) {
    s += __shfl_xor(s, o, 64);
    s2 += __shfl_xor(s2, o, 64);
  }
  if ((tid & 63) == 0) { red1[tid >> 6] = s; red2[tid >> 6] = s2; }
  __syncthreads();
  s = red1[0] + red1[1] + red1[2] + red1[3];
  s2 = red2[0] + red2[1] + red2[2] + red2[3];
  const float mean = s * (1.0f / 768.0f);
  const float var = s2 * (1.0f / 768.0f) - mean * mean;
  const float rstd = rsqrtf(var + 1e-12f);
  float* xr = x + (size_t)tok * H_;
  __bf16* xbr = xb + (size_t)tok * H_;
  const float y0 = (v0 - mean) * rstd * g[tid] + bb[tid];
  const float y1 = (v1 - mean) * rstd * g[tid + 256] + bb[tid + 256];
  const float y2 = (v2 - mean) * rstd * g[tid + 512] + bb[tid + 512];
  xr[tid] = y0; xr[tid + 256] = y1; xr[tid + 512] = y2;
  xbr[tid] = (__bf16)y0; xbr[tid + 256] = (__bf16)y1; xbr[tid + 512] = (__bf16)y2;
}

// ---------------------------------------------------------------------------
// Pooler: pooled[b] = tanh(x[b,0,:] @ poolW + pool_b).
// ---------------------------------------------------------------------------
__global__ __launch_bounds__(256) void pool_kernel(const float* __restrict__ x,
                                                   const __bf16* __restrict__ wT,
                                                   const float* __restrict__ pb,
                                                   float* __restrict__ out) {
  const int b = blockIdx.x, tid = threadIdx.x;
  __shared__ float xr[H_];
  for (int i = tid; i < H_; i += 256) xr[i] = x[(size_t)b * S_ * H_ + i];
  __syncthreads();
  for (int n = tid; n < H_; n += 256) {
    const __bf16* w = wT + (size_t)n * H_;
    float acc = 0.f;
    for (int k = 0; k < H_; ++k) acc += xr[k] * (float)w[k];
    out[(size_t)b * H_ + n] = tanhf(acc + pb[n]);
  }
}

// ---------------------------------------------------------------------------
extern "C" void kernel_launch(void* const* d_in, const int* in_sizes, int n_in,
                              void* d_out, int out_size, void* d_ws,
                              size_t ws_size, hipStream_t stream) {
  (void)in_sizes; (void)n_in; (void)out_size;
  const int* ids = (const int*)d_in[0];
  const int* am = (const int*)d_in[1];
  const int* tt = (const int*)d_in[2];
  const float* we = (const float*)d_in[3];
  const float* se = (const float*)d_in[4];
  const float* pe = (const float*)d_in[5];
  const float* te = (const float*)d_in[6];
  const float* eg = (const float*)d_in[7];
  const float* ebb = (const float*)d_in[8];
  const float* Wq = (const float*)d_in[9];
  const float* bq = (const float*)d_in[10];
  const float* Wk = (const float*)d_in[11];
  const float* bk = (const float*)d_in[12];
  const float* Wv = (const float*)d_in[13];
  const float* bv = (const float*)d_in[14];
  const float* Wo = (const float*)d_in[15];
  const float* bo = (const float*)d_in[16];
  const float* g1 = (const float*)d_in[17];
  const float* b1 = (const float*)d_in[18];
  const float* Wi = (const float*)d_in[19];
  const float* bi = (const float*)d_in[20];
  const float* Wf = (const float*)d_in[21];
  const float* bf_ = (const float*)d_in[22];
  const float* g2 = (const float*)d_in[23];
  const float* b2 = (const float*)d_in[24];
  const float* pw = (const float*)d_in[25];
  const float* pb = (const float*)d_in[26];

  const size_t WQKV = (size_t)L_ * QKVN * H_;
  const size_t WSQ = (size_t)L_ * H_ * H_;
  const size_t WSF = (size_t)L_ * H_ * F_;
  const size_t MN = (size_t)NTOK * H_;
  __bf16* wqkv = (__bf16*)d_ws;
  __bf16* wTo_ = wqkv + WQKV;
  __bf16* wTi_ = wTo_ + WSQ;
  __bf16* wTf_ = wTi_ + WSF;
  __bf16* wTp_ = wTf_ + WSF;
  __bf16* xb = wTp_ + (size_t)H_ * H_;
  __bf16* qkvb = xb + MN;
  __bf16* cb = qkvb + (size_t)NTOK * QKVN;
  __bf16* mid = cb + MN;
  __bf16* vtb = mid + (size_t)NTOK * F_;
  __bf16* t0b = vtb + MN;               // AO/FF2 bf16 output (12.6 MB)
  float* bqkv = (float*)(t0b + MN);
  const size_t needed = (size_t)((char*)(bqkv + (size_t)L_ * QKVN) - (char*)d_ws);
  if (ws_size < needed) return;  // insufficient scratch: visible failure

  float* x = (float*)d_out;
  float* pooled = x + MN;

  const dim3 tb(32, 8);
  const size_t zq = (size_t)QKVN * H_;
  transpose_k<<<dim3(24, 24, 12), tb, 0, stream>>>(Wq, wqkv, H_, H_, zq);
  transpose_k<<<dim3(24, 24, 12), tb, 0, stream>>>(Wk, wqkv + (size_t)H_ * H_, H_, H_, zq);
  transpose_k<<<dim3(24, 24, 12), tb, 0, stream>>>(Wv, wqkv + 2 * (size_t)H_ * H_, H_, H_, zq);
  transpose_k<<<dim3(24, 24, 12), tb, 0, stream>>>(Wo, wTo_, H_, H_, (size_t)H_ * H_);
  transpose_k<<<dim3(96, 24, 12), tb, 0, stream>>>(Wi, wTi_, H_, F_, (size_t)H_ * F_);
  transpose_k<<<dim3(24, 96, 12), tb, 0, stream>>>(Wf, wTf_, F_, H_, (size_t)H_ * F_);
  transpose_k<<<dim3(24, 24, 1), tb, 0, stream>>>(pw, wTp_, H_, H_, (size_t)H_ * H_);
  concat_bias<<<(L_ * QKVN + 255) / 256, 256, 0, stream>>>(bq, bk, bv, bqkv);

  embed_kernel<<<NTOK, 256, 0, stream>>>(ids, tt, we, se, pe, te, eg, ebb, x, xb);

  for (int l = 0; l < L_; ++l) {
    // fused QKV (V written transposed in-epilogue): 2304 blocks
    gemm_n64<0, 1, 1><<<(NTOK / 128) * (QKVN / 64), 256, 0, stream>>>(
        xb, wqkv + (size_t)l * QKVN * H_, bqkv + (size_t)l * QKVN,
        nullptr, qkvb, vtb, NTOK, QKVN, H_, QKVN / 64);

    attn_kernel<<<NH_ * B_ * 4, 256, 0, stream>>>(qkvb, vtb, am, cb);

    // attn-out: 768 blocks; bf16 output
    gemm_n64<0, 1, 0><<<(NTOK / 128) * (H_ / 64), 256, 0, stream>>>(
        cb, wTo_ + (size_t)l * H_ * H_, bo + l * H_, nullptr, t0b, nullptr,
        NTOK, H_, H_, H_ / 64);
    addln_kernel<<<NTOK / 4, 256, 0, stream>>>(x, t0b, g1 + l * H_, b1 + l * H_, xb);

    // FF1: 3072 blocks (fast GELU epilogue)
    gemm_n64<1, 1, 0><<<(NTOK / 128) * (F_ / 64), 256, 0, stream>>>(
        xb, wTi_ + (size_t)l * H_ * F_, bi + l * F_, nullptr, mid, nullptr,
        NTOK, F_, H_, F_ / 64);
    // FF2: 768 blocks; bf16 output
    gemm_n64<0, 1, 0><<<(NTOK / 128) * (H_ / 64), 256, 0, stream>>>(
        mid, wTf_ + (size_t)l * F_ * H_, bf_ + l * H_, nullptr, t0b, nullptr,
        NTOK, H_, F_, H_ / 64);
    addln_kernel<<<NTOK / 4, 256, 0, stream>>>(x, t0b, g2 + l * H_, b2 + l * H_, xb);
  }

  pool_kernel<<<B_, 256, 0, stream>>>(x, wTp_, pb, pooled);
}

// Round 20
// 2961.092 us; speedup vs baseline: 1.0458x; 1.0263x over previous
//
#include <hip/hip_runtime.h>
#include <hip/hip_bf16.h>
#include <math.h>

// ---------------------------------------------------------------------------
// KVPLM Star Encoder: 12 layers, H=768, NH=12, F=3072, B=16, S=512.
// Round 20: attn KV-tile 32 -> 64 keys/iteration (8 iters): halves barrier/
// vmcnt/softmax-reduce/rescale event counts at constant MFMA work. LDS 52 KB
// (still 3 blocks/CU). GEMMs/LN frozen (gemm_n64, fast GELU, fused V^T).
// ---------------------------------------------------------------------------

#define L_   12
#define H_   768
#define NH_  12
#define DH_  64
#define F_   3072
#define B_   16
#define S_   512
#define NTOK (B_ * S_)   // 8192
#define QKVN 2304

typedef __attribute__((ext_vector_type(8))) __bf16 bf16x8;
typedef __attribute__((ext_vector_type(4))) __bf16 bf16x4;
typedef __attribute__((ext_vector_type(4))) float  f32x4;

static __device__ __forceinline__ f32x4 mfma16(bf16x8 a, bf16x8 b, f32x4 c) {
  return __builtin_amdgcn_mfma_f32_16x16x32_bf16(a, b, c, 0, 0, 0);
}

static __device__ __forceinline__ void load_lds16(const void* g, void* l) {
  __builtin_amdgcn_global_load_lds(
      (const __attribute__((address_space(1))) void*)g,
      (__attribute__((address_space(3))) void*)l, 16, 0, 0);
}

// tanh-approx GELU (max dev vs exact ~4e-4, under bf16 rounding)
static __device__ __forceinline__ float gelu_fast(float v) {
  const float u = 1.5957691216057308f * v * (1.0f + 0.044715f * v * v);
  return v / (1.0f + __expf(-u));
}

// ---------------------------------------------------------------------------
// Weight transpose+convert: in fp32 [Z][R][C] -> out bf16 [Z (stride outZ)][C][R]
// ---------------------------------------------------------------------------
__global__ __launch_bounds__(256) void transpose_k(const float* __restrict__ in,
                                                   __bf16* __restrict__ out,
                                                   int R, int C, size_t outZ) {
  __shared__ float t[32][33];
  const int z = blockIdx.z;
  const float* inz = in + (size_t)z * R * C;
  __bf16* outz = out + (size_t)z * outZ;
  const int c0 = blockIdx.x * 32, r0 = blockIdx.y * 32;
  const int tx = threadIdx.x, ty = threadIdx.y;
#pragma unroll
  for (int i = 0; i < 32; i += 8)
    t[ty + i][tx] = inz[(size_t)(r0 + ty + i) * C + c0 + tx];
  __syncthreads();
#pragma unroll
  for (int i = 0; i < 32; i += 8)
    outz[(size_t)(c0 + ty + i) * R + r0 + tx] = (__bf16)t[tx][ty + i];
}

__global__ __launch_bounds__(256) void concat_bias(const float* __restrict__ bq,
                                                   const float* __restrict__ bk,
                                                   const float* __restrict__ bv,
                                                   float* __restrict__ o) {
  const int i = blockIdx.x * 256 + threadIdx.x;
  if (i >= L_ * QKVN) return;
  const int l = i / QKVN, j = i - l * QKVN;
  float v;
  if (j < H_) v = bq[l * H_ + j];
  else if (j < 2 * H_) v = bk[l * H_ + j - H_];
  else v = bv[l * H_ + j - 2 * H_];
  o[i] = v;
}

// ---------------------------------------------------------------------------
// gemm_n64 (R13 local optimum): 2-phase 128x64 GEMM, BK=64, LDS 48 KiB dbuf
// -> 3 blocks/CU. T2 st_16x32 swizzle + T3-minimal schedule. VT=1 (QKV):
// cols >= 2H write transposed into vtp[(b*NH+h)*64+d][s] (bf16x4 per frag).
// ---------------------------------------------------------------------------
template <int EPI, int OUTBF, int VT>
__global__ __launch_bounds__(256, 3) void gemm_n64(const __bf16* __restrict__ A,
                                                   const __bf16* __restrict__ Bt,
                                                   const float* __restrict__ bias,
                                                   float* __restrict__ Cf,
                                                   __bf16* __restrict__ Cb,
                                                   __bf16* __restrict__ vtp,
                                                   int M, int N, int K, int Ntiles) {
  alignas(16) __shared__ __bf16 lds[24576];  // [buf2][A 8192 | B 4096] el
  const int tid = threadIdx.x, wid = tid >> 6, lane = tid & 63;
  int bid = blockIdx.x;
  const int nwg = gridDim.x;
  if ((nwg & 7) == 0) bid = (bid & 7) * (nwg >> 3) + (bid >> 3);  // XCD swizzle
  const int bm = (bid / Ntiles) << 7, bn = (bid % Ntiles) << 6;
  const int nt = K >> 6;

  const __bf16* pA[4];
  const __bf16* pB[2];
#pragma unroll
  for (int j = 0; j < 4; ++j) {
    const int E = (j << 11) + tid * 8;
    const int Ep = E ^ (((E >> 8) & 1) << 4);
    const int r = ((Ep >> 10) << 4) | ((Ep >> 5) & 15);
    const int c = (((Ep >> 9) & 1) << 5) | (Ep & 31);
    pA[j] = A + (size_t)(bm + r) * K + c;
    if (j < 2) pB[j] = Bt + (size_t)(bn + r) * K + c;  // r < 64 for E < 4096
  }

  auto stage = [&](int t, int buf) {
    __bf16* base = &lds[buf * 12288 + (wid << 9)];
    const size_t off = (size_t)(t << 6);
#pragma unroll
    for (int j = 0; j < 4; ++j) load_lds16(pA[j] + off, base + (j << 11));
#pragma unroll
    for (int j = 0; j < 2; ++j) load_lds16(pB[j] + off, base + 8192 + (j << 11));
  };

  const int frow = lane & 15, fk = (lane >> 4) << 3;
  const int swzb = (frow * 32 + fk) ^ (((frow >> 3) & 1) << 4);
  const int mh = wid >> 1, nq = wid & 1;  // wave tile 64x32

  f32x4 acc[4][2] = {};

  stage(0, 0);
  asm volatile("s_waitcnt vmcnt(0)" ::: "memory");
  __builtin_amdgcn_s_barrier();

  for (int t = 0; t < nt; ++t) {
    const int buf = t & 1;
    if (t + 1 < nt) stage(t + 1, buf ^ 1);   // issue BEFORE ds_read+MFMA
    const __bf16* LA = &lds[buf * 12288 + (mh << 12)];
    const __bf16* LB = &lds[buf * 12288 + 8192 + (nq << 11)];
    bf16x8 a[4][2], b[2][2];
#pragma unroll
    for (int mi = 0; mi < 4; ++mi)
#pragma unroll
      for (int ks = 0; ks < 2; ++ks)
        a[mi][ks] = *(const bf16x8*)&LA[mi * 1024 + ks * 512 + swzb];
#pragma unroll
    for (int ni = 0; ni < 2; ++ni)
#pragma unroll
      for (int ks = 0; ks < 2; ++ks)
        b[ni][ks] = *(const bf16x8*)&LB[ni * 1024 + ks * 512 + swzb];
    asm volatile("s_waitcnt lgkmcnt(0)" ::: "memory");
    __builtin_amdgcn_s_setprio(1);
#pragma unroll
    for (int mi = 0; mi < 4; ++mi)
#pragma unroll
      for (int ni = 0; ni < 2; ++ni)
#pragma unroll
        for (int ks = 0; ks < 2; ++ks)
          acc[mi][ni] = mfma16(a[mi][ks], b[ni][ks], acc[mi][ni]);
    __builtin_amdgcn_s_setprio(0);
    asm volatile("s_waitcnt vmcnt(0)" ::: "memory");  // next tile staged
    __builtin_amdgcn_s_barrier();
  }

  // epilogue: C/D layout col=lane&15, row=(lane>>4)*4+r  [m89 verified]
  const int r0 = (lane >> 4) << 2, c0 = lane & 15;
  const int wrow = bm + (mh << 6), wcol = bn + (nq << 5);
#pragma unroll
  for (int ni = 0; ni < 2; ++ni) {
    const int col = wcol + (ni << 4) + c0;
    const float bv = bias[col];
    if (VT && (wcol + (ni << 4)) >= 2 * H_) {
      const int hh = (col - 2 * H_) >> 6, dd = (col - 2 * H_) & 63;
#pragma unroll
      for (int mi = 0; mi < 4; ++mi) {
        const int row = wrow + (mi << 4) + r0;
        bf16x4 pv;
#pragma unroll
        for (int r = 0; r < 4; ++r) pv[r] = (__bf16)(acc[mi][ni][r] + bv);
        const int bb2 = row >> 9, ss = row & 511;
        *(bf16x4*)&vtp[((size_t)(bb2 * NH_ + hh) * DH_ + dd) * S_ + ss] = pv;
      }
    } else {
#pragma unroll
      for (int mi = 0; mi < 4; ++mi) {
        const int row = wrow + (mi << 4) + r0;
#pragma unroll
        for (int r = 0; r < 4; ++r) {
          float v = acc[mi][ni][r] + bv;
          if (EPI == 1) v = gelu_fast(v);
          if (OUTBF)
            Cb[(size_t)(row + r) * N + col] = (__bf16)v;
          else
            Cf[(size_t)(row + r) * N + col] = v;
        }
      }
    }
  }
}

// ---------------------------------------------------------------------------
// Flash attention, swapped QK^T, TWO q-tiles/wave, 64-KEY KV tiles (8 iters):
// per iteration {stage(kt+1): 4 loads -> ds_read frags -> 2x(QK 8-MFMA,
// 16-val softmax reduce, P roundtrip, PV 8-MFMA) -> vmcnt(0) -> barrier}.
// LDS 52 KB -> 3 blocks/CU. Grid 768 linear, XCD-chunked.
// ---------------------------------------------------------------------------
__global__ __launch_bounds__(256, 3) void attn_kernel(const __bf16* __restrict__ qkv,
                                                      const __bf16* __restrict__ vt,
                                                      const int* __restrict__ amask,
                                                      __bf16* __restrict__ ctx) {
  __shared__ float extm[S_];                      // 2 KB
  alignas(16) __shared__ __bf16 Kl[2][4096];      // 16 KB [buf][rg4|cg2|16|32]
  alignas(16) __shared__ __bf16 Vl[2][4096];      // 16 KB [buf][ks2|dt4|16|32]
  __shared__ __bf16 Pl[4][2][16][72];             // 18 KB (pad 64->72)
  const int swz = ((int)blockIdx.x & 7) * 96 + ((int)blockIdx.x >> 3);
  const int z = swz & 3;
  const int hb = swz >> 2;
  const int h = hb % NH_, b = hb / NH_;
  const int tid = threadIdx.x, wid = tid >> 6, lane = tid & 63;
  const size_t rowb = (size_t)b * S_ * QKVN + (size_t)h * DH_;
  const __bf16* vbase = vt + ((size_t)(b * NH_ + h) * DH_) * S_;

  for (int i = tid; i < S_; i += 256)
    extm[i] = (1.0f - (float)amask[b * S_ + i]) * -10000.0f;

  // per-thread staging source coords (inverse st_16x32 swizzle, rule #21)
  // K: two 2048-el loads span keys 0..63 (Ep>>10 in 0..3).
  const __bf16* ksrc[2];
#pragma unroll
  for (int j = 0; j < 2; ++j) {
    const int E = (j << 11) + tid * 8;
    const int Ep = E ^ (((E >> 8) & 1) << 4);
    const int kr = ((Ep >> 10) << 4) | ((Ep >> 5) & 15);   // key 0..63
    const int kc = (((Ep >> 9) & 1) << 5) | (Ep & 31);     // d
    ksrc[j] = qkv + rowb + (size_t)kr * QKVN + H_ + kc;
  }
  // V: per 2048-el region [dt4|16|32]; region j covers s-chunk j*32..+31.
  const __bf16* vsrc;
  {
    const int e = tid * 8;
    const int ep = e ^ (((e >> 8) & 1) << 4);
    const int vd = ((ep >> 9) << 4) | ((ep >> 5) & 15);    // d
    const int vs = ep & 31;                                // s within 32-chunk
    vsrc = vbase + (size_t)vd * S_ + vs;
  }

  auto stageKV = [&](int kt, int buf) {
    load_lds16(ksrc[0] + (size_t)(kt * 64) * QKVN, &Kl[buf][tid * 8]);
    load_lds16(ksrc[1] + (size_t)(kt * 64) * QKVN, &Kl[buf][2048 + tid * 8]);
    load_lds16(vsrc + kt * 64, &Vl[buf][tid * 8]);
    load_lds16(vsrc + kt * 64 + 32, &Vl[buf][2048 + tid * 8]);
  };

  const int c0 = lane & 15, g4 = lane >> 4;
  const int swzb = (c0 * 32 + (g4 << 3)) ^ (((c0 >> 3) & 1) << 4);
  const int qt0 = z * 8 + wid * 2;   // this wave's two q-tiles
  bf16x8 qf[2][2];
#pragma unroll
  for (int qi = 0; qi < 2; ++qi) {
    const __bf16* qrow = qkv + rowb +
        (size_t)((qt0 + qi) * 16 + c0) * QKVN + (g4 << 3);
    qf[qi][0] = *(const bf16x8*)qrow;
    qf[qi][1] = *(const bf16x8*)(qrow + 32);
  }
  f32x4 oacc[2][4] = {};
  float mrow[2] = {-1e30f, -1e30f}, lsum[2] = {0.f, 0.f};

  stageKV(0, 0);
  asm volatile("s_waitcnt vmcnt(0)" ::: "memory");
  __syncthreads();   // extm + KV tile 0 ready

#pragma unroll
  for (int kt = 0; kt < 8; ++kt) {
    const int buf = kt & 1;
    if (kt + 1 < 8) stageKV(kt + 1, buf ^ 1);   // issue BEFORE compute
    bf16x8 kf[4][2], vf[2][4];
#pragma unroll
    for (int f = 0; f < 4; ++f)
#pragma unroll
      for (int half = 0; half < 2; ++half)
        kf[f][half] = *(const bf16x8*)&Kl[buf][f * 1024 + half * 512 + swzb];
#pragma unroll
    for (int ks = 0; ks < 2; ++ks)
#pragma unroll
      for (int dt = 0; dt < 4; ++dt)
        vf[ks][dt] = *(const bf16x8*)&Vl[buf][ks * 2048 + dt * 512 + swzb];
    asm volatile("s_waitcnt lgkmcnt(0)" ::: "memory");
#pragma unroll
    for (int qi = 0; qi < 2; ++qi) {
      f32x4 sc[4];
      __builtin_amdgcn_s_setprio(1);
#pragma unroll
      for (int f = 0; f < 4; ++f) {
        f32x4 z2 = {};
        z2 = mfma16(kf[f][0], qf[qi][0], z2);   // SWAPPED: C[m=key][n=q]
        z2 = mfma16(kf[f][1], qf[qi][1], z2);
#pragma unroll
        for (int r = 0; r < 4; ++r)
          sc[f][r] = z2[r] * 0.125f + extm[kt * 64 + f * 16 + (g4 << 2) + r];
      }
      __builtin_amdgcn_s_setprio(0);
      float mx = sc[0][0];
#pragma unroll
      for (int f = 0; f < 4; ++f)
#pragma unroll
        for (int r = 0; r < 4; ++r) mx = fmaxf(mx, sc[f][r]);
      mx = fmaxf(mx, __shfl_xor(mx, 16, 64));
      mx = fmaxf(mx, __shfl_xor(mx, 32, 64));
      const float mn = fmaxf(mrow[qi], mx);
      const float al = __expf(mrow[qi] - mn);
      mrow[qi] = mn;
      float rs = 0.f;
#pragma unroll
      for (int f = 0; f < 4; ++f) {
        bf16x4 pv;
#pragma unroll
        for (int r = 0; r < 4; ++r) {
          const float p = __expf(sc[f][r] - mn);
          pv[r] = (__bf16)p;
          rs += p;
        }
        *(bf16x4*)&Pl[wid][qi][c0][f * 16 + (g4 << 2)] = pv;
      }
      rs += __shfl_xor(rs, 16, 64);
      rs += __shfl_xor(rs, 32, 64);
      lsum[qi] = lsum[qi] * al + rs;
      float alr[4];
#pragma unroll
      for (int r = 0; r < 4; ++r)
        alr[r] = __shfl(al, (lane & 48) | ((g4 << 2) + r), 64);
#pragma unroll
      for (int dt = 0; dt < 4; ++dt)
#pragma unroll
        for (int r = 0; r < 4; ++r) oacc[qi][dt][r] *= alr[r];
      const bf16x8 pa0 = *(const bf16x8*)&Pl[wid][qi][c0][g4 << 3];
      const bf16x8 pa1 = *(const bf16x8*)&Pl[wid][qi][c0][32 + (g4 << 3)];
      __builtin_amdgcn_s_setprio(1);
#pragma unroll
      for (int dt = 0; dt < 4; ++dt) {
        oacc[qi][dt] = mfma16(pa0, vf[0][dt], oacc[qi][dt]);
        oacc[qi][dt] = mfma16(pa1, vf[1][dt], oacc[qi][dt]);
      }
      __builtin_amdgcn_s_setprio(0);
    }
    asm volatile("s_waitcnt vmcnt(0)" ::: "memory");  // next KV tile staged
    __builtin_amdgcn_s_barrier();
  }
#pragma unroll
  for (int qi = 0; qi < 2; ++qi) {
    float inv[4];
#pragma unroll
    for (int r = 0; r < 4; ++r)
      inv[r] = 1.0f / __shfl(lsum[qi], (lane & 48) | ((g4 << 2) + r), 64);
#pragma unroll
    for (int dt = 0; dt < 4; ++dt)
#pragma unroll
      for (int r = 0; r < 4; ++r)
        ctx[(size_t)b * S_ * H_ + (size_t)h * DH_ +
            (size_t)((qt0 + qi) * 16 + (g4 << 2) + r) * H_ + dt * 16 + c0] =
            (__bf16)(oacc[qi][dt][r] * inv[r]);
  }
}

// ---------------------------------------------------------------------------
// Residual add + LayerNorm, ONE WAVE PER TOKEN. t is bf16 (half traffic).
// ---------------------------------------------------------------------------
__global__ __launch_bounds__(256) void addln_kernel(float* __restrict__ x,
                                                    const __bf16* __restrict__ t,
                                                    const float* __restrict__ g,
                                                    const float* __restrict__ bb,
                                                    __bf16* __restrict__ xb) {
  const int tok = blockIdx.x * 4 + (threadIdx.x >> 6);
  const int lane = threadIdx.x & 63;
  float* xr = x + (size_t)tok * H_;
  const __bf16* tr = t + (size_t)tok * H_;
  f32x4 v[3];
  float s = 0.f, s2 = 0.f;
#pragma unroll
  for (int i = 0; i < 3; ++i) {
    const int off = lane * 4 + i * 256;
    f32x4 a = *(const f32x4*)&xr[off];
    bf16x4 tb = *(const bf16x4*)&tr[off];
#pragma unroll
    for (int r = 0; r < 4; ++r) {
      v[i][r] = a[r] + (float)tb[r];
      s += v[i][r];
      s2 += v[i][r] * v[i][r];
    }
  }
#pragma unroll
  for (int o = 32; o > 0; o >>= 1) {
    s += __shfl_xor(s, o, 64);
    s2 += __shfl_xor(s2, o, 64);
  }
  const float mean = s * (1.0f / 768.0f);
  const float var = s2 * (1.0f / 768.0f) - mean * mean;
  const float rstd = rsqrtf(var + 1e-12f);
  __bf16* xbr = xb + (size_t)tok * H_;
#pragma unroll
  for (int i = 0; i < 3; ++i) {
    const int off = lane * 4 + i * 256;
    f32x4 gv = *(const f32x4*)&g[off];
    f32x4 bv = *(const f32x4*)&bb[off];
    f32x4 y;
    bf16x4 yb;
#pragma unroll
    for (int r = 0; r < 4; ++r) {
      y[r] = (v[i][r] - mean) * rstd * gv[r] + bv[r];
      yb[r] = (__bf16)y[r];
    }
    *(f32x4*)&xr[off] = y;
    *(bf16x4*)&xbr[off] = yb;
  }
}

// ---------------------------------------------------------------------------
// Embedding (word/star select + pos + type) + LN.
// ---------------------------------------------------------------------------
__global__ __launch_bounds__(256) void embed_kernel(
    const int* __restrict__ ids, const int* __restrict__ tt,
    const float* __restrict__ we, const float* __restrict__ se,
    const float* __restrict__ pe, const float* __restrict__ te,
    const float* __restrict__ g, const float* __restrict__ bb,
    float* __restrict__ x, __bf16* __restrict__ xb) {
  const int tok = blockIdx.x, tid = threadIdx.x;
  const int sp = tok & (S_ - 1);
  const int id = ids[tok];
  const float* e = (id >= 30700) ? se + (size_t)(id - 30700) * H_
                                 : we + (size_t)id * H_;
  const float* pr = pe + (size_t)sp * H_;
  const float* ty = te + (size_t)tt[tok] * H_;
  float v0 = e[tid] + pr[tid] + ty[tid];
  float v1 = e[tid + 256] + pr[tid + 256] + ty[tid + 256];
  float v2 = e[tid + 512] + pr[tid + 512] + ty[tid + 512];
  float s = v0 + v1 + v2;
  float s2 = v0 * v0 + v1 * v1 + v2 * v2;
  __shared__ float red1[4], red2[4];
#pragma unroll
  for (int o = 32; o > 0; o >>= 1) {
    s += __shfl_xor(s, o, 64);
    s2 += __shfl_xor(s2, o, 64);
  }
  if ((tid & 63) == 0) { red1[tid >> 6] = s; red2[tid >> 6] = s2; }
  __syncthreads();
  s = red1[0] + red1[1] + red1[2] + red1[3];
  s2 = red2[0] + red2[1] + red2[2] + red2[3];
  const float mean = s * (1.0f / 768.0f);
  const float var = s2 * (1.0f / 768.0f) - mean * mean;
  const float rstd = rsqrtf(var + 1e-12f);
  float* xr = x + (size_t)tok * H_;
  __bf16* xbr = xb + (size_t)tok * H_;
  const float y0 = (v0 - mean) * rstd * g[tid] + bb[tid];
  const float y1 = (v1 - mean) * rstd * g[tid + 256] + bb[tid + 256];
  const float y2 = (v2 - mean) * rstd * g[tid + 512] + bb[tid + 512];
  xr[tid] = y0; xr[tid + 256] = y1; xr[tid + 512] = y2;
  xbr[tid] = (__bf16)y0; xbr[tid + 256] = (__bf16)y1; xbr[tid + 512] = (__bf16)y2;
}

// ---------------------------------------------------------------------------
// Pooler: pooled[b] = tanh(x[b,0,:] @ poolW + pool_b).
// ---------------------------------------------------------------------------
__global__ __launch_bounds__(256) void pool_kernel(const float* __restrict__ x,
                                                   const __bf16* __restrict__ wT,
                                                   const float* __restrict__ pb,
                                                   float* __restrict__ out) {
  const int b = blockIdx.x, tid = threadIdx.x;
  __shared__ float xr[H_];
  for (int i = tid; i < H_; i += 256) xr[i] = x[(size_t)b * S_ * H_ + i];
  __syncthreads();
  for (int n = tid; n < H_; n += 256) {
    const __bf16* w = wT + (size_t)n * H_;
    float acc = 0.f;
    for (int k = 0; k < H_; ++k) acc += xr[k] * (float)w[k];
    out[(size_t)b * H_ + n] = tanhf(acc + pb[n]);
  }
}

// ---------------------------------------------------------------------------
extern "C" void kernel_launch(void* const* d_in, const int* in_sizes, int n_in,
                              void* d_out, int out_size, void* d_ws,
                              size_t ws_size, hipStream_t stream) {
  (void)in_sizes; (void)n_in; (void)out_size;
  const int* ids = (const int*)d_in[0];
  const int* am = (const int*)d_in[1];
  const int* tt = (const int*)d_in[2];
  const float* we = (const float*)d_in[3];
  const float* se = (const float*)d_in[4];
  const float* pe = (const float*)d_in[5];
  const float* te = (const float*)d_in[6];
  const float* eg = (const float*)d_in[7];
  const float* ebb = (const float*)d_in[8];
  const float* Wq = (const float*)d_in[9];
  const float* bq = (const float*)d_in[10];
  const float* Wk = (const float*)d_in[11];
  const float* bk = (const float*)d_in[12];
  const float* Wv = (const float*)d_in[13];
  const float* bv = (const float*)d_in[14];
  const float* Wo = (const float*)d_in[15];
  const float* bo = (const float*)d_in[16];
  const float* g1 = (const float*)d_in[17];
  const float* b1 = (const float*)d_in[18];
  const float* Wi = (const float*)d_in[19];
  const float* bi = (const float*)d_in[20];
  const float* Wf = (const float*)d_in[21];
  const float* bf_ = (const float*)d_in[22];
  const float* g2 = (const float*)d_in[23];
  const float* b2 = (const float*)d_in[24];
  const float* pw = (const float*)d_in[25];
  const float* pb = (const float*)d_in[26];

  const size_t WQKV = (size_t)L_ * QKVN * H_;
  const size_t WSQ = (size_t)L_ * H_ * H_;
  const size_t WSF = (size_t)L_ * H_ * F_;
  const size_t MN = (size_t)NTOK * H_;
  __bf16* wqkv = (__bf16*)d_ws;
  __bf16* wTo_ = wqkv + WQKV;
  __bf16* wTi_ = wTo_ + WSQ;
  __bf16* wTf_ = wTi_ + WSF;
  __bf16* wTp_ = wTf_ + WSF;
  __bf16* xb = wTp_ + (size_t)H_ * H_;
  __bf16* qkvb = xb + MN;
  __bf16* cb = qkvb + (size_t)NTOK * QKVN;
  __bf16* mid = cb + MN;
  __bf16* vtb = mid + (size_t)NTOK * F_;
  __bf16* t0b = vtb + MN;               // AO/FF2 bf16 output (12.6 MB)
  float* bqkv = (float*)(t0b + MN);
  const size_t needed = (size_t)((char*)(bqkv + (size_t)L_ * QKVN) - (char*)d_ws);
  if (ws_size < needed) return;  // insufficient scratch: visible failure

  float* x = (float*)d_out;
  float* pooled = x + MN;

  const dim3 tb(32, 8);
  const size_t zq = (size_t)QKVN * H_;
  transpose_k<<<dim3(24, 24, 12), tb, 0, stream>>>(Wq, wqkv, H_, H_, zq);
  transpose_k<<<dim3(24, 24, 12), tb, 0, stream>>>(Wk, wqkv + (size_t)H_ * H_, H_, H_, zq);
  transpose_k<<<dim3(24, 24, 12), tb, 0, stream>>>(Wv, wqkv + 2 * (size_t)H_ * H_, H_, H_, zq);
  transpose_k<<<dim3(24, 24, 12), tb, 0, stream>>>(Wo, wTo_, H_, H_, (size_t)H_ * H_);
  transpose_k<<<dim3(96, 24, 12), tb, 0, stream>>>(Wi, wTi_, H_, F_, (size_t)H_ * F_);
  transpose_k<<<dim3(24, 96, 12), tb, 0, stream>>>(Wf, wTf_, F_, H_, (size_t)H_ * F_);
  transpose_k<<<dim3(24, 24, 1), tb, 0, stream>>>(pw, wTp_, H_, H_, (size_t)H_ * H_);
  concat_bias<<<(L_ * QKVN + 255) / 256, 256, 0, stream>>>(bq, bk, bv, bqkv);

  embed_kernel<<<NTOK, 256, 0, stream>>>(ids, tt, we, se, pe, te, eg, ebb, x, xb);

  for (int l = 0; l < L_; ++l) {
    // fused QKV (V written transposed in-epilogue): 2304 blocks
    gemm_n64<0, 1, 1><<<(NTOK / 128) * (QKVN / 64), 256, 0, stream>>>(
        xb, wqkv + (size_t)l * QKVN * H_, bqkv + (size_t)l * QKVN,
        nullptr, qkvb, vtb, NTOK, QKVN, H_, QKVN / 64);

    attn_kernel<<<NH_ * B_ * 4, 256, 0, stream>>>(qkvb, vtb, am, cb);

    // attn-out: 768 blocks; bf16 output
    gemm_n64<0, 1, 0><<<(NTOK / 128) * (H_ / 64), 256, 0, stream>>>(
        cb, wTo_ + (size_t)l * H_ * H_, bo + l * H_, nullptr, t0b, nullptr,
        NTOK, H_, H_, H_ / 64);
    addln_kernel<<<NTOK / 4, 256, 0, stream>>>(x, t0b, g1 + l * H_, b1 + l * H_, xb);

    // FF1: 3072 blocks (fast GELU epilogue)
    gemm_n64<1, 1, 0><<<(NTOK / 128) * (F_ / 64), 256, 0, stream>>>(
        xb, wTi_ + (size_t)l * H_ * F_, bi + l * F_, nullptr, mid, nullptr,
        NTOK, F_, H_, F_ / 64);
    // FF2: 768 blocks; bf16 output
    gemm_n64<0, 1, 0><<<(NTOK / 128) * (H_ / 64), 256, 0, stream>>>(
        mid, wTf_ + (size_t)l * F_ * H_, bf_ + l * H_, nullptr, t0b, nullptr,
        NTOK, H_, F_, H_ / 64);
    addln_kernel<<<NTOK / 4, 256, 0, stream>>>(x, t0b, g2 + l * H_, b2 + l * H_, xb);
  }

  pool_kernel<<<B_, 256, 0, stream>>>(x, wTp_, pb, pooled);
}

// Round 21
// 2933.627 us; speedup vs baseline: 1.0556x; 1.0094x over previous
//
#include <hip/hip_runtime.h>
#include <hip/hip_bf16.h>
#include <math.h>

// ---------------------------------------------------------------------------
// KVPLM Star Encoder: 12 layers, H=768, NH=12, F=3072, B=16, S=512.
// Round 21: T13 defer-max in attention (skip O-rescale when tile max growth
// <= 8; wave-uniform __all branch). Everything else frozen at R20:
// gemm_n64 (128x64xBK64, 3/CU), 64-key attn tiles, fast GELU, fused V^T.
// ---------------------------------------------------------------------------

#define L_   12
#define H_   768
#define NH_  12
#define DH_  64
#define F_   3072
#define B_   16
#define S_   512
#define NTOK (B_ * S_)   // 8192
#define QKVN 2304

typedef __attribute__((ext_vector_type(8))) __bf16 bf16x8;
typedef __attribute__((ext_vector_type(4))) __bf16 bf16x4;
typedef __attribute__((ext_vector_type(4))) float  f32x4;

static __device__ __forceinline__ f32x4 mfma16(bf16x8 a, bf16x8 b, f32x4 c) {
  return __builtin_amdgcn_mfma_f32_16x16x32_bf16(a, b, c, 0, 0, 0);
}

static __device__ __forceinline__ void load_lds16(const void* g, void* l) {
  __builtin_amdgcn_global_load_lds(
      (const __attribute__((address_space(1))) void*)g,
      (__attribute__((address_space(3))) void*)l, 16, 0, 0);
}

// tanh-approx GELU (max dev vs exact ~4e-4, under bf16 rounding)
static __device__ __forceinline__ float gelu_fast(float v) {
  const float u = 1.5957691216057308f * v * (1.0f + 0.044715f * v * v);
  return v / (1.0f + __expf(-u));
}

// ---------------------------------------------------------------------------
// Weight transpose+convert: in fp32 [Z][R][C] -> out bf16 [Z (stride outZ)][C][R]
// ---------------------------------------------------------------------------
__global__ __launch_bounds__(256) void transpose_k(const float* __restrict__ in,
                                                   __bf16* __restrict__ out,
                                                   int R, int C, size_t outZ) {
  __shared__ float t[32][33];
  const int z = blockIdx.z;
  const float* inz = in + (size_t)z * R * C;
  __bf16* outz = out + (size_t)z * outZ;
  const int c0 = blockIdx.x * 32, r0 = blockIdx.y * 32;
  const int tx = threadIdx.x, ty = threadIdx.y;
#pragma unroll
  for (int i = 0; i < 32; i += 8)
    t[ty + i][tx] = inz[(size_t)(r0 + ty + i) * C + c0 + tx];
  __syncthreads();
#pragma unroll
  for (int i = 0; i < 32; i += 8)
    outz[(size_t)(c0 + ty + i) * R + r0 + tx] = (__bf16)t[tx][ty + i];
}

__global__ __launch_bounds__(256) void concat_bias(const float* __restrict__ bq,
                                                   const float* __restrict__ bk,
                                                   const float* __restrict__ bv,
                                                   float* __restrict__ o) {
  const int i = blockIdx.x * 256 + threadIdx.x;
  if (i >= L_ * QKVN) return;
  const int l = i / QKVN, j = i - l * QKVN;
  float v;
  if (j < H_) v = bq[l * H_ + j];
  else if (j < 2 * H_) v = bk[l * H_ + j - H_];
  else v = bv[l * H_ + j - 2 * H_];
  o[i] = v;
}

// ---------------------------------------------------------------------------
// gemm_n64 (R13 local optimum): 2-phase 128x64 GEMM, BK=64, LDS 48 KiB dbuf
// -> 3 blocks/CU. T2 st_16x32 swizzle + T3-minimal schedule. VT=1 (QKV):
// cols >= 2H write transposed into vtp[(b*NH+h)*64+d][s] (bf16x4 per frag).
// ---------------------------------------------------------------------------
template <int EPI, int OUTBF, int VT>
__global__ __launch_bounds__(256, 3) void gemm_n64(const __bf16* __restrict__ A,
                                                   const __bf16* __restrict__ Bt,
                                                   const float* __restrict__ bias,
                                                   float* __restrict__ Cf,
                                                   __bf16* __restrict__ Cb,
                                                   __bf16* __restrict__ vtp,
                                                   int M, int N, int K, int Ntiles) {
  alignas(16) __shared__ __bf16 lds[24576];  // [buf2][A 8192 | B 4096] el
  const int tid = threadIdx.x, wid = tid >> 6, lane = tid & 63;
  int bid = blockIdx.x;
  const int nwg = gridDim.x;
  if ((nwg & 7) == 0) bid = (bid & 7) * (nwg >> 3) + (bid >> 3);  // XCD swizzle
  const int bm = (bid / Ntiles) << 7, bn = (bid % Ntiles) << 6;
  const int nt = K >> 6;

  const __bf16* pA[4];
  const __bf16* pB[2];
#pragma unroll
  for (int j = 0; j < 4; ++j) {
    const int E = (j << 11) + tid * 8;
    const int Ep = E ^ (((E >> 8) & 1) << 4);
    const int r = ((Ep >> 10) << 4) | ((Ep >> 5) & 15);
    const int c = (((Ep >> 9) & 1) << 5) | (Ep & 31);
    pA[j] = A + (size_t)(bm + r) * K + c;
    if (j < 2) pB[j] = Bt + (size_t)(bn + r) * K + c;  // r < 64 for E < 4096
  }

  auto stage = [&](int t, int buf) {
    __bf16* base = &lds[buf * 12288 + (wid << 9)];
    const size_t off = (size_t)(t << 6);
#pragma unroll
    for (int j = 0; j < 4; ++j) load_lds16(pA[j] + off, base + (j << 11));
#pragma unroll
    for (int j = 0; j < 2; ++j) load_lds16(pB[j] + off, base + 8192 + (j << 11));
  };

  const int frow = lane & 15, fk = (lane >> 4) << 3;
  const int swzb = (frow * 32 + fk) ^ (((frow >> 3) & 1) << 4);
  const int mh = wid >> 1, nq = wid & 1;  // wave tile 64x32

  f32x4 acc[4][2] = {};

  stage(0, 0);
  asm volatile("s_waitcnt vmcnt(0)" ::: "memory");
  __builtin_amdgcn_s_barrier();

  for (int t = 0; t < nt; ++t) {
    const int buf = t & 1;
    if (t + 1 < nt) stage(t + 1, buf ^ 1);   // issue BEFORE ds_read+MFMA
    const __bf16* LA = &lds[buf * 12288 + (mh << 12)];
    const __bf16* LB = &lds[buf * 12288 + 8192 + (nq << 11)];
    bf16x8 a[4][2], b[2][2];
#pragma unroll
    for (int mi = 0; mi < 4; ++mi)
#pragma unroll
      for (int ks = 0; ks < 2; ++ks)
        a[mi][ks] = *(const bf16x8*)&LA[mi * 1024 + ks * 512 + swzb];
#pragma unroll
    for (int ni = 0; ni < 2; ++ni)
#pragma unroll
      for (int ks = 0; ks < 2; ++ks)
        b[ni][ks] = *(const bf16x8*)&LB[ni * 1024 + ks * 512 + swzb];
    asm volatile("s_waitcnt lgkmcnt(0)" ::: "memory");
    __builtin_amdgcn_s_setprio(1);
#pragma unroll
    for (int mi = 0; mi < 4; ++mi)
#pragma unroll
      for (int ni = 0; ni < 2; ++ni)
#pragma unroll
        for (int ks = 0; ks < 2; ++ks)
          acc[mi][ni] = mfma16(a[mi][ks], b[ni][ks], acc[mi][ni]);
    __builtin_amdgcn_s_setprio(0);
    asm volatile("s_waitcnt vmcnt(0)" ::: "memory");  // next tile staged
    __builtin_amdgcn_s_barrier();
  }

  // epilogue: C/D layout col=lane&15, row=(lane>>4)*4+r  [m89 verified]
  const int r0 = (lane >> 4) << 2, c0 = lane & 15;
  const int wrow = bm + (mh << 6), wcol = bn + (nq << 5);
#pragma unroll
  for (int ni = 0; ni < 2; ++ni) {
    const int col = wcol + (ni << 4) + c0;
    const float bv = bias[col];
    if (VT && (wcol + (ni << 4)) >= 2 * H_) {
      const int hh = (col - 2 * H_) >> 6, dd = (col - 2 * H_) & 63;
#pragma unroll
      for (int mi = 0; mi < 4; ++mi) {
        const int row = wrow + (mi << 4) + r0;
        bf16x4 pv;
#pragma unroll
        for (int r = 0; r < 4; ++r) pv[r] = (__bf16)(acc[mi][ni][r] + bv);
        const int bb2 = row >> 9, ss = row & 511;
        *(bf16x4*)&vtp[((size_t)(bb2 * NH_ + hh) * DH_ + dd) * S_ + ss] = pv;
      }
    } else {
#pragma unroll
      for (int mi = 0; mi < 4; ++mi) {
        const int row = wrow + (mi << 4) + r0;
#pragma unroll
        for (int r = 0; r < 4; ++r) {
          float v = acc[mi][ni][r] + bv;
          if (EPI == 1) v = gelu_fast(v);
          if (OUTBF)
            Cb[(size_t)(row + r) * N + col] = (__bf16)v;
          else
            Cf[(size_t)(row + r) * N + col] = v;
        }
      }
    }
  }
}

// ---------------------------------------------------------------------------
// Flash attention, swapped QK^T, TWO q-tiles/wave, 64-KEY KV tiles (8 iters),
// T13 defer-max (skip O-rescale when tile max growth <= 8; uniform branch).
// LDS 52 KB -> 3 blocks/CU. Grid 768 linear, XCD-chunked.
// ---------------------------------------------------------------------------
__global__ __launch_bounds__(256, 3) void attn_kernel(const __bf16* __restrict__ qkv,
                                                      const __bf16* __restrict__ vt,
                                                      const int* __restrict__ amask,
                                                      __bf16* __restrict__ ctx) {
  __shared__ float extm[S_];                      // 2 KB
  alignas(16) __shared__ __bf16 Kl[2][4096];      // 16 KB [buf][rg4|cg2|16|32]
  alignas(16) __shared__ __bf16 Vl[2][4096];      // 16 KB [buf][ks2|dt4|16|32]
  __shared__ __bf16 Pl[4][2][16][72];             // 18 KB (pad 64->72)
  const int swz = ((int)blockIdx.x & 7) * 96 + ((int)blockIdx.x >> 3);
  const int z = swz & 3;
  const int hb = swz >> 2;
  const int h = hb % NH_, b = hb / NH_;
  const int tid = threadIdx.x, wid = tid >> 6, lane = tid & 63;
  const size_t rowb = (size_t)b * S_ * QKVN + (size_t)h * DH_;
  const __bf16* vbase = vt + ((size_t)(b * NH_ + h) * DH_) * S_;

  for (int i = tid; i < S_; i += 256)
    extm[i] = (1.0f - (float)amask[b * S_ + i]) * -10000.0f;

  // per-thread staging source coords (inverse st_16x32 swizzle, rule #21)
  const __bf16* ksrc[2];
#pragma unroll
  for (int j = 0; j < 2; ++j) {
    const int E = (j << 11) + tid * 8;
    const int Ep = E ^ (((E >> 8) & 1) << 4);
    const int kr = ((Ep >> 10) << 4) | ((Ep >> 5) & 15);   // key 0..63
    const int kc = (((Ep >> 9) & 1) << 5) | (Ep & 31);     // d
    ksrc[j] = qkv + rowb + (size_t)kr * QKVN + H_ + kc;
  }
  const __bf16* vsrc;
  {
    const int e = tid * 8;
    const int ep = e ^ (((e >> 8) & 1) << 4);
    const int vd = ((ep >> 9) << 4) | ((ep >> 5) & 15);    // d
    const int vs = ep & 31;                                // s within 32-chunk
    vsrc = vbase + (size_t)vd * S_ + vs;
  }

  auto stageKV = [&](int kt, int buf) {
    load_lds16(ksrc[0] + (size_t)(kt * 64) * QKVN, &Kl[buf][tid * 8]);
    load_lds16(ksrc[1] + (size_t)(kt * 64) * QKVN, &Kl[buf][2048 + tid * 8]);
    load_lds16(vsrc + kt * 64, &Vl[buf][tid * 8]);
    load_lds16(vsrc + kt * 64 + 32, &Vl[buf][2048 + tid * 8]);
  };

  const int c0 = lane & 15, g4 = lane >> 4;
  const int swzb = (c0 * 32 + (g4 << 3)) ^ (((c0 >> 3) & 1) << 4);
  const int qt0 = z * 8 + wid * 2;   // this wave's two q-tiles
  bf16x8 qf[2][2];
#pragma unroll
  for (int qi = 0; qi < 2; ++qi) {
    const __bf16* qrow = qkv + rowb +
        (size_t)((qt0 + qi) * 16 + c0) * QKVN + (g4 << 3);
    qf[qi][0] = *(const bf16x8*)qrow;
    qf[qi][1] = *(const bf16x8*)(qrow + 32);
  }
  f32x4 oacc[2][4] = {};
  float mrow[2] = {-1e30f, -1e30f}, lsum[2] = {0.f, 0.f};

  stageKV(0, 0);
  asm volatile("s_waitcnt vmcnt(0)" ::: "memory");
  __syncthreads();   // extm + KV tile 0 ready

#pragma unroll
  for (int kt = 0; kt < 8; ++kt) {
    const int buf = kt & 1;
    if (kt + 1 < 8) stageKV(kt + 1, buf ^ 1);   // issue BEFORE compute
    bf16x8 kf[4][2], vf[2][4];
#pragma unroll
    for (int f = 0; f < 4; ++f)
#pragma unroll
      for (int half = 0; half < 2; ++half)
        kf[f][half] = *(const bf16x8*)&Kl[buf][f * 1024 + half * 512 + swzb];
#pragma unroll
    for (int ks = 0; ks < 2; ++ks)
#pragma unroll
      for (int dt = 0; dt < 4; ++dt)
        vf[ks][dt] = *(const bf16x8*)&Vl[buf][ks * 2048 + dt * 512 + swzb];
    asm volatile("s_waitcnt lgkmcnt(0)" ::: "memory");
#pragma unroll
    for (int qi = 0; qi < 2; ++qi) {
      f32x4 sc[4];
      __builtin_amdgcn_s_setprio(1);
#pragma unroll
      for (int f = 0; f < 4; ++f) {
        f32x4 z2 = {};
        z2 = mfma16(kf[f][0], qf[qi][0], z2);   // SWAPPED: C[m=key][n=q]
        z2 = mfma16(kf[f][1], qf[qi][1], z2);
#pragma unroll
        for (int r = 0; r < 4; ++r)
          sc[f][r] = z2[r] * 0.125f + extm[kt * 64 + f * 16 + (g4 << 2) + r];
      }
      __builtin_amdgcn_s_setprio(0);
      float mx = sc[0][0];
#pragma unroll
      for (int f = 0; f < 4; ++f)
#pragma unroll
        for (int r = 0; r < 4; ++r) mx = fmaxf(mx, sc[f][r]);
      mx = fmaxf(mx, __shfl_xor(mx, 16, 64));
      mx = fmaxf(mx, __shfl_xor(mx, 32, 64));
      // T13 defer-max: only rescale when tile max exceeds running max by >8.
      const bool need = !__all(mx - mrow[qi] <= 8.0f);
      float al = 1.0f;
      if (need) {
        const float mn = fmaxf(mrow[qi], mx);
        al = __expf(mrow[qi] - mn);
        mrow[qi] = mn;
      }
      float rs = 0.f;
#pragma unroll
      for (int f = 0; f < 4; ++f) {
        bf16x4 pv;
#pragma unroll
        for (int r = 0; r < 4; ++r) {
          const float p = __expf(sc[f][r] - mrow[qi]);
          pv[r] = (__bf16)p;
          rs += p;
        }
        *(bf16x4*)&Pl[wid][qi][c0][f * 16 + (g4 << 2)] = pv;
      }
      rs += __shfl_xor(rs, 16, 64);
      rs += __shfl_xor(rs, 32, 64);
      lsum[qi] = lsum[qi] * al + rs;
      if (need) {
        float alr[4];
#pragma unroll
        for (int r = 0; r < 4; ++r)
          alr[r] = __shfl(al, (lane & 48) | ((g4 << 2) + r), 64);
#pragma unroll
        for (int dt = 0; dt < 4; ++dt)
#pragma unroll
          for (int r = 0; r < 4; ++r) oacc[qi][dt][r] *= alr[r];
      }
      const bf16x8 pa0 = *(const bf16x8*)&Pl[wid][qi][c0][g4 << 3];
      const bf16x8 pa1 = *(const bf16x8*)&Pl[wid][qi][c0][32 + (g4 << 3)];
      __builtin_amdgcn_s_setprio(1);
#pragma unroll
      for (int dt = 0; dt < 4; ++dt) {
        oacc[qi][dt] = mfma16(pa0, vf[0][dt], oacc[qi][dt]);
        oacc[qi][dt] = mfma16(pa1, vf[1][dt], oacc[qi][dt]);
      }
      __builtin_amdgcn_s_setprio(0);
    }
    asm volatile("s_waitcnt vmcnt(0)" ::: "memory");  // next KV tile staged
    __builtin_amdgcn_s_barrier();
  }
#pragma unroll
  for (int qi = 0; qi < 2; ++qi) {
    float inv[4];
#pragma unroll
    for (int r = 0; r < 4; ++r)
      inv[r] = 1.0f / __shfl(lsum[qi], (lane & 48) | ((g4 << 2) + r), 64);
#pragma unroll
    for (int dt = 0; dt < 4; ++dt)
#pragma unroll
      for (int r = 0; r < 4; ++r)
        ctx[(size_t)b * S_ * H_ + (size_t)h * DH_ +
            (size_t)((qt0 + qi) * 16 + (g4 << 2) + r) * H_ + dt * 16 + c0] =
            (__bf16)(oacc[qi][dt][r] * inv[r]);
  }
}

// ---------------------------------------------------------------------------
// Residual add + LayerNorm, ONE WAVE PER TOKEN. t is bf16 (half traffic).
// ---------------------------------------------------------------------------
__global__ __launch_bounds__(256) void addln_kernel(float* __restrict__ x,
                                                    const __bf16* __restrict__ t,
                                                    const float* __restrict__ g,
                                                    const float* __restrict__ bb,
                                                    __bf16* __restrict__ xb) {
  const int tok = blockIdx.x * 4 + (threadIdx.x >> 6);
  const int lane = threadIdx.x & 63;
  float* xr = x + (size_t)tok * H_;
  const __bf16* tr = t + (size_t)tok * H_;
  f32x4 v[3];
  float s = 0.f, s2 = 0.f;
#pragma unroll
  for (int i = 0; i < 3; ++i) {
    const int off = lane * 4 + i * 256;
    f32x4 a = *(const f32x4*)&xr[off];
    bf16x4 tb = *(const bf16x4*)&tr[off];
#pragma unroll
    for (int r = 0; r < 4; ++r) {
      v[i][r] = a[r] + (float)tb[r];
      s += v[i][r];
      s2 += v[i][r] * v[i][r];
    }
  }
#pragma unroll
  for (int o = 32; o > 0; o >>= 1) {
    s += __shfl_xor(s, o, 64);
    s2 += __shfl_xor(s2, o, 64);
  }
  const float mean = s * (1.0f / 768.0f);
  const float var = s2 * (1.0f / 768.0f) - mean * mean;
  const float rstd = rsqrtf(var + 1e-12f);
  __bf16* xbr = xb + (size_t)tok * H_;
#pragma unroll
  for (int i = 0; i < 3; ++i) {
    const int off = lane * 4 + i * 256;
    f32x4 gv = *(const f32x4*)&g[off];
    f32x4 bv = *(const f32x4*)&bb[off];
    f32x4 y;
    bf16x4 yb;
#pragma unroll
    for (int r = 0; r < 4; ++r) {
      y[r] = (v[i][r] - mean) * rstd * gv[r] + bv[r];
      yb[r] = (__bf16)y[r];
    }
    *(f32x4*)&xr[off] = y;
    *(bf16x4*)&xbr[off] = yb;
  }
}

// ---------------------------------------------------------------------------
// Embedding (word/star select + pos + type) + LN.
// ---------------------------------------------------------------------------
__global__ __launch_bounds__(256) void embed_kernel(
    const int* __restrict__ ids, const int* __restrict__ tt,
    const float* __restrict__ we, const float* __restrict__ se,
    const float* __restrict__ pe, const float* __restrict__ te,
    const float* __restrict__ g, const float* __restrict__ bb,
    float* __restrict__ x, __bf16* __restrict__ xb) {
  const int tok = blockIdx.x, tid = threadIdx.x;
  const int sp = tok & (S_ - 1);
  const int id = ids[tok];
  const float* e = (id >= 30700) ? se + (size_t)(id - 30700) * H_
                                 : we + (size_t)id * H_;
  const float* pr = pe + (size_t)sp * H_;
  const float* ty = te + (size_t)tt[tok] * H_;
  float v0 = e[tid] + pr[tid] + ty[tid];
  float v1 = e[tid + 256] + pr[tid + 256] + ty[tid + 256];
  float v2 = e[tid + 512] + pr[tid + 512] + ty[tid + 512];
  float s = v0 + v1 + v2;
  float s2 = v0 * v0 + v1 * v1 + v2 * v2;
  __shared__ float red1[4], red2[4];
#pragma unroll
  for (int o = 32; o > 0; o >>= 1) {
    s += __shfl_xor(s, o, 64);
    s2 += __shfl_xor(s2, o, 64);
  }
  if ((tid & 63) == 0) { red1[tid >> 6] = s; red2[tid >> 6] = s2; }
  __syncthreads();
  s = red1[0] + red1[1] + red1[2] + red1[3];
  s2 = red2[0] + red2[1] + red2[2] + red2[3];
  const float mean = s * (1.0f / 768.0f);
  const float var = s2 * (1.0f / 768.0f) - mean * mean;
  const float rstd = rsqrtf(var + 1e-12f);
  float* xr = x + (size_t)tok * H_;
  __bf16* xbr = xb + (size_t)tok * H_;
  const float y0 = (v0 - mean) * rstd * g[tid] + bb[tid];
  const float y1 = (v1 - mean) * rstd * g[tid + 256] + bb[tid + 256];
  const float y2 = (v2 - mean) * rstd * g[tid + 512] + bb[tid + 512];
  xr[tid] = y0; xr[tid + 256] = y1; xr[tid + 512] = y2;
  xbr[tid] = (__bf16)y0; xbr[tid + 256] = (__bf16)y1; xbr[tid + 512] = (__bf16)y2;
}

// ---------------------------------------------------------------------------
// Pooler: pooled[b] = tanh(x[b,0,:] @ poolW + pool_b).
// ---------------------------------------------------------------------------
__global__ __launch_bounds__(256) void pool_kernel(const float* __restrict__ x,
                                                   const __bf16* __restrict__ wT,
                                                   const float* __restrict__ pb,
                                                   float* __restrict__ out) {
  const int b = blockIdx.x, tid = threadIdx.x;
  __shared__ float xr[H_];
  for (int i = tid; i < H_; i += 256) xr[i] = x[(size_t)b * S_ * H_ + i];
  __syncthreads();
  for (int n = tid; n < H_; n += 256) {
    const __bf16* w = wT + (size_t)n * H_;
    float acc = 0.f;
    for (int k = 0; k < H_; ++k) acc += xr[k] * (float)w[k];
    out[(size_t)b * H_ + n] = tanhf(acc + pb[n]);
  }
}

// ---------------------------------------------------------------------------
extern "C" void kernel_launch(void* const* d_in, const int* in_sizes, int n_in,
                              void* d_out, int out_size, void* d_ws,
                              size_t ws_size, hipStream_t stream) {
  (void)in_sizes; (void)n_in; (void)out_size;
  const int* ids = (const int*)d_in[0];
  const int* am = (const int*)d_in[1];
  const int* tt = (const int*)d_in[2];
  const float* we = (const float*)d_in[3];
  const float* se = (const float*)d_in[4];
  const float* pe = (const float*)d_in[5];
  const float* te = (const float*)d_in[6];
  const float* eg = (const float*)d_in[7];
  const float* ebb = (const float*)d_in[8];
  const float* Wq = (const float*)d_in[9];
  const float* bq = (const float*)d_in[10];
  const float* Wk = (const float*)d_in[11];
  const float* bk = (const float*)d_in[12];
  const float* Wv = (const float*)d_in[13];
  const float* bv = (const float*)d_in[14];
  const float* Wo = (const float*)d_in[15];
  const float* bo = (const float*)d_in[16];
  const float* g1 = (const float*)d_in[17];
  const float* b1 = (const float*)d_in[18];
  const float* Wi = (const float*)d_in[19];
  const float* bi = (const float*)d_in[20];
  const float* Wf = (const float*)d_in[21];
  const float* bf_ = (const float*)d_in[22];
  const float* g2 = (const float*)d_in[23];
  const float* b2 = (const float*)d_in[24];
  const float* pw = (const float*)d_in[25];
  const float* pb = (const float*)d_in[26];

  const size_t WQKV = (size_t)L_ * QKVN * H_;
  const size_t WSQ = (size_t)L_ * H_ * H_;
  const size_t WSF = (size_t)L_ * H_ * F_;
  const size_t MN = (size_t)NTOK * H_;
  __bf16* wqkv = (__bf16*)d_ws;
  __bf16* wTo_ = wqkv + WQKV;
  __bf16* wTi_ = wTo_ + WSQ;
  __bf16* wTf_ = wTi_ + WSF;
  __bf16* wTp_ = wTf_ + WSF;
  __bf16* xb = wTp_ + (size_t)H_ * H_;
  __bf16* qkvb = xb + MN;
  __bf16* cb = qkvb + (size_t)NTOK * QKVN;
  __bf16* mid = cb + MN;
  __bf16* vtb = mid + (size_t)NTOK * F_;
  __bf16* t0b = vtb + MN;               // AO/FF2 bf16 output (12.6 MB)
  float* bqkv = (float*)(t0b + MN);
  const size_t needed = (size_t)((char*)(bqkv + (size_t)L_ * QKVN) - (char*)d_ws);
  if (ws_size < needed) return;  // insufficient scratch: visible failure

  float* x = (float*)d_out;
  float* pooled = x + MN;

  const dim3 tb(32, 8);
  const size_t zq = (size_t)QKVN * H_;
  transpose_k<<<dim3(24, 24, 12), tb, 0, stream>>>(Wq, wqkv, H_, H_, zq);
  transpose_k<<<dim3(24, 24, 12), tb, 0, stream>>>(Wk, wqkv + (size_t)H_ * H_, H_, H_, zq);
  transpose_k<<<dim3(24, 24, 12), tb, 0, stream>>>(Wv, wqkv + 2 * (size_t)H_ * H_, H_, H_, zq);
  transpose_k<<<dim3(24, 24, 12), tb, 0, stream>>>(Wo, wTo_, H_, H_, (size_t)H_ * H_);
  transpose_k<<<dim3(96, 24, 12), tb, 0, stream>>>(Wi, wTi_, H_, F_, (size_t)H_ * F_);
  transpose_k<<<dim3(24, 96, 12), tb, 0, stream>>>(Wf, wTf_, F_, H_, (size_t)H_ * F_);
  transpose_k<<<dim3(24, 24, 1), tb, 0, stream>>>(pw, wTp_, H_, H_, (size_t)H_ * H_);
  concat_bias<<<(L_ * QKVN + 255) / 256, 256, 0, stream>>>(bq, bk, bv, bqkv);

  embed_kernel<<<NTOK, 256, 0, stream>>>(ids, tt, we, se, pe, te, eg, ebb, x, xb);

  for (int l = 0; l < L_; ++l) {
    // fused QKV (V written transposed in-epilogue): 2304 blocks
    gemm_n64<0, 1, 1><<<(NTOK / 128) * (QKVN / 64), 256, 0, stream>>>(
        xb, wqkv + (size_t)l * QKVN * H_, bqkv + (size_t)l * QKVN,
        nullptr, qkvb, vtb, NTOK, QKVN, H_, QKVN / 64);

    attn_kernel<<<NH_ * B_ * 4, 256, 0, stream>>>(qkvb, vtb, am, cb);

    // attn-out: 768 blocks; bf16 output
    gemm_n64<0, 1, 0><<<(NTOK / 128) * (H_ / 64), 256, 0, stream>>>(
        cb, wTo_ + (size_t)l * H_ * H_, bo + l * H_, nullptr, t0b, nullptr,
        NTOK, H_, H_, H_ / 64);
    addln_kernel<<<NTOK / 4, 256, 0, stream>>>(x, t0b, g1 + l * H_, b1 + l * H_, xb);

    // FF1: 3072 blocks (fast GELU epilogue)
    gemm_n64<1, 1, 0><<<(NTOK / 128) * (F_ / 64), 256, 0, stream>>>(
        xb, wTi_ + (size_t)l * H_ * F_, bi + l * F_, nullptr, mid, nullptr,
        NTOK, F_, H_, F_ / 64);
    // FF2: 768 blocks; bf16 output
    gemm_n64<0, 1, 0><<<(NTOK / 128) * (H_ / 64), 256, 0, stream>>>(
        mid, wTf_ + (size_t)l * F_ * H_, bf_ + l * H_, nullptr, t0b, nullptr,
        NTOK, H_, F_, H_ / 64);
    addln_kernel<<<NTOK / 4, 256, 0, stream>>>(x, t0b, g2 + l * H_, b2 + l * H_, xb);
  }

  pool_kernel<<<B_, 256, 0, stream>>>(x, wTp_, pb, pooled);
}

// Round 22
// 2854.900 us; speedup vs baseline: 1.0847x; 1.0276x over previous
//
#include <hip/hip_runtime.h>
#include <hip/hip_bf16.h>
#include <math.h>

// ---------------------------------------------------------------------------
// KVPLM Star Encoder: 12 layers, H=768, NH=12, F=3072, B=16, S=512.
// Round 22: grouped-N raster in gemm_n64 — N-sweep split into groups whose
// B-panel (Gn*64*K*2B) fits a 4MB XCD L2; iterate (group, M, n-in-group).
// R21 counters: FF1 FETCH 84 MB vs 17 compulsory = B thrash (4.7MB > L2).
// Gn: QKV 18, AO 12, FF1 24, FF2 6. All else frozen at R21.
// ---------------------------------------------------------------------------

#define L_   12
#define H_   768
#define NH_  12
#define DH_  64
#define F_   3072
#define B_   16
#define S_   512
#define NTOK (B_ * S_)   // 8192
#define QKVN 2304

typedef __attribute__((ext_vector_type(8))) __bf16 bf16x8;
typedef __attribute__((ext_vector_type(4))) __bf16 bf16x4;
typedef __attribute__((ext_vector_type(4))) float  f32x4;

static __device__ __forceinline__ f32x4 mfma16(bf16x8 a, bf16x8 b, f32x4 c) {
  return __builtin_amdgcn_mfma_f32_16x16x32_bf16(a, b, c, 0, 0, 0);
}

static __device__ __forceinline__ void load_lds16(const void* g, void* l) {
  __builtin_amdgcn_global_load_lds(
      (const __attribute__((address_space(1))) void*)g,
      (__attribute__((address_space(3))) void*)l, 16, 0, 0);
}

// tanh-approx GELU (max dev vs exact ~4e-4, under bf16 rounding)
static __device__ __forceinline__ float gelu_fast(float v) {
  const float u = 1.5957691216057308f * v * (1.0f + 0.044715f * v * v);
  return v / (1.0f + __expf(-u));
}

// ---------------------------------------------------------------------------
// Weight transpose+convert: in fp32 [Z][R][C] -> out bf16 [Z (stride outZ)][C][R]
// ---------------------------------------------------------------------------
__global__ __launch_bounds__(256) void transpose_k(const float* __restrict__ in,
                                                   __bf16* __restrict__ out,
                                                   int R, int C, size_t outZ) {
  __shared__ float t[32][33];
  const int z = blockIdx.z;
  const float* inz = in + (size_t)z * R * C;
  __bf16* outz = out + (size_t)z * outZ;
  const int c0 = blockIdx.x * 32, r0 = blockIdx.y * 32;
  const int tx = threadIdx.x, ty = threadIdx.y;
#pragma unroll
  for (int i = 0; i < 32; i += 8)
    t[ty + i][tx] = inz[(size_t)(r0 + ty + i) * C + c0 + tx];
  __syncthreads();
#pragma unroll
  for (int i = 0; i < 32; i += 8)
    outz[(size_t)(c0 + ty + i) * R + r0 + tx] = (__bf16)t[tx][ty + i];
}

__global__ __launch_bounds__(256) void concat_bias(const float* __restrict__ bq,
                                                   const float* __restrict__ bk,
                                                   const float* __restrict__ bv,
                                                   float* __restrict__ o) {
  const int i = blockIdx.x * 256 + threadIdx.x;
  if (i >= L_ * QKVN) return;
  const int l = i / QKVN, j = i - l * QKVN;
  float v;
  if (j < H_) v = bq[l * H_ + j];
  else if (j < 2 * H_) v = bk[l * H_ + j - H_];
  else v = bv[l * H_ + j - 2 * H_];
  o[i] = v;
}

// ---------------------------------------------------------------------------
// gemm_n64: 2-phase 128x64 GEMM, BK=64, LDS 48 KiB dbuf -> 3 blocks/CU.
// T2 st_16x32 swizzle + T3-minimal schedule. Grouped-N raster: Gn N-tiles
// per group (B-panel <= ~2.4MB, L2-resident); order (group, M, n-in-group).
// VT=1 (QKV): cols >= 2H write transposed into vtp (bf16x4 per frag).
// ---------------------------------------------------------------------------
template <int EPI, int OUTBF, int VT>
__global__ __launch_bounds__(256, 3) void gemm_n64(const __bf16* __restrict__ A,
                                                   const __bf16* __restrict__ Bt,
                                                   const float* __restrict__ bias,
                                                   float* __restrict__ Cf,
                                                   __bf16* __restrict__ Cb,
                                                   __bf16* __restrict__ vtp,
                                                   int M, int N, int K,
                                                   int Ntiles, int Gn) {
  alignas(16) __shared__ __bf16 lds[24576];  // [buf2][A 8192 | B 4096] el
  const int tid = threadIdx.x, wid = tid >> 6, lane = tid & 63;
  int bid = blockIdx.x;
  const int nwg = gridDim.x;
  if ((nwg & 7) == 0) bid = (bid & 7) * (nwg >> 3) + (bid >> 3);  // XCD swizzle
  // grouped-N raster: (group, M, n-within-group)
  const int Mtiles = M >> 7;
  const int gsz = Mtiles * Gn;
  const int grp = bid / gsz;
  const int within = bid - grp * gsz;
  const int bm = (within / Gn) << 7;
  const int bn = (grp * Gn + (within % Gn)) << 6;
  const int nt = K >> 6;

  const __bf16* pA[4];
  const __bf16* pB[2];
#pragma unroll
  for (int j = 0; j < 4; ++j) {
    const int E = (j << 11) + tid * 8;
    const int Ep = E ^ (((E >> 8) & 1) << 4);
    const int r = ((Ep >> 10) << 4) | ((Ep >> 5) & 15);
    const int c = (((Ep >> 9) & 1) << 5) | (Ep & 31);
    pA[j] = A + (size_t)(bm + r) * K + c;
    if (j < 2) pB[j] = Bt + (size_t)(bn + r) * K + c;  // r < 64 for E < 4096
  }

  auto stage = [&](int t, int buf) {
    __bf16* base = &lds[buf * 12288 + (wid << 9)];
    const size_t off = (size_t)(t << 6);
#pragma unroll
    for (int j = 0; j < 4; ++j) load_lds16(pA[j] + off, base + (j << 11));
#pragma unroll
    for (int j = 0; j < 2; ++j) load_lds16(pB[j] + off, base + 8192 + (j << 11));
  };

  const int frow = lane & 15, fk = (lane >> 4) << 3;
  const int swzb = (frow * 32 + fk) ^ (((frow >> 3) & 1) << 4);
  const int mh = wid >> 1, nq = wid & 1;  // wave tile 64x32

  f32x4 acc[4][2] = {};

  stage(0, 0);
  asm volatile("s_waitcnt vmcnt(0)" ::: "memory");
  __builtin_amdgcn_s_barrier();

  for (int t = 0; t < nt; ++t) {
    const int buf = t & 1;
    if (t + 1 < nt) stage(t + 1, buf ^ 1);   // issue BEFORE ds_read+MFMA
    const __bf16* LA = &lds[buf * 12288 + (mh << 12)];
    const __bf16* LB = &lds[buf * 12288 + 8192 + (nq << 11)];
    bf16x8 a[4][2], b[2][2];
#pragma unroll
    for (int mi = 0; mi < 4; ++mi)
#pragma unroll
      for (int ks = 0; ks < 2; ++ks)
        a[mi][ks] = *(const bf16x8*)&LA[mi * 1024 + ks * 512 + swzb];
#pragma unroll
    for (int ni = 0; ni < 2; ++ni)
#pragma unroll
      for (int ks = 0; ks < 2; ++ks)
        b[ni][ks] = *(const bf16x8*)&LB[ni * 1024 + ks * 512 + swzb];
    asm volatile("s_waitcnt lgkmcnt(0)" ::: "memory");
    __builtin_amdgcn_s_setprio(1);
#pragma unroll
    for (int mi = 0; mi < 4; ++mi)
#pragma unroll
      for (int ni = 0; ni < 2; ++ni)
#pragma unroll
        for (int ks = 0; ks < 2; ++ks)
          acc[mi][ni] = mfma16(a[mi][ks], b[ni][ks], acc[mi][ni]);
    __builtin_amdgcn_s_setprio(0);
    asm volatile("s_waitcnt vmcnt(0)" ::: "memory");  // next tile staged
    __builtin_amdgcn_s_barrier();
  }

  // epilogue: C/D layout col=lane&15, row=(lane>>4)*4+r  [m89 verified]
  const int r0 = (lane >> 4) << 2, c0 = lane & 15;
  const int wrow = bm + (mh << 6), wcol = bn + (nq << 5);
#pragma unroll
  for (int ni = 0; ni < 2; ++ni) {
    const int col = wcol + (ni << 4) + c0;
    const float bv = bias[col];
    if (VT && (wcol + (ni << 4)) >= 2 * H_) {
      const int hh = (col - 2 * H_) >> 6, dd = (col - 2 * H_) & 63;
#pragma unroll
      for (int mi = 0; mi < 4; ++mi) {
        const int row = wrow + (mi << 4) + r0;
        bf16x4 pv;
#pragma unroll
        for (int r = 0; r < 4; ++r) pv[r] = (__bf16)(acc[mi][ni][r] + bv);
        const int bb2 = row >> 9, ss = row & 511;
        *(bf16x4*)&vtp[((size_t)(bb2 * NH_ + hh) * DH_ + dd) * S_ + ss] = pv;
      }
    } else {
#pragma unroll
      for (int mi = 0; mi < 4; ++mi) {
        const int row = wrow + (mi << 4) + r0;
#pragma unroll
        for (int r = 0; r < 4; ++r) {
          float v = acc[mi][ni][r] + bv;
          if (EPI == 1) v = gelu_fast(v);
          if (OUTBF)
            Cb[(size_t)(row + r) * N + col] = (__bf16)v;
          else
            Cf[(size_t)(row + r) * N + col] = v;
        }
      }
    }
  }
}

// ---------------------------------------------------------------------------
// Flash attention, swapped QK^T, TWO q-tiles/wave, 64-KEY KV tiles (8 iters),
// T13 defer-max. LDS 52 KB -> 3 blocks/CU. Grid 768 linear, XCD-chunked.
// ---------------------------------------------------------------------------
__global__ __launch_bounds__(256, 3) void attn_kernel(const __bf16* __restrict__ qkv,
                                                      const __bf16* __restrict__ vt,
                                                      const int* __restrict__ amask,
                                                      __bf16* __restrict__ ctx) {
  __shared__ float extm[S_];                      // 2 KB
  alignas(16) __shared__ __bf16 Kl[2][4096];      // 16 KB
  alignas(16) __shared__ __bf16 Vl[2][4096];      // 16 KB
  __shared__ __bf16 Pl[4][2][16][72];             // 18 KB (pad 64->72)
  const int swz = ((int)blockIdx.x & 7) * 96 + ((int)blockIdx.x >> 3);
  const int z = swz & 3;
  const int hb = swz >> 2;
  const int h = hb % NH_, b = hb / NH_;
  const int tid = threadIdx.x, wid = tid >> 6, lane = tid & 63;
  const size_t rowb = (size_t)b * S_ * QKVN + (size_t)h * DH_;
  const __bf16* vbase = vt + ((size_t)(b * NH_ + h) * DH_) * S_;

  for (int i = tid; i < S_; i += 256)
    extm[i] = (1.0f - (float)amask[b * S_ + i]) * -10000.0f;

  const __bf16* ksrc[2];
#pragma unroll
  for (int j = 0; j < 2; ++j) {
    const int E = (j << 11) + tid * 8;
    const int Ep = E ^ (((E >> 8) & 1) << 4);
    const int kr = ((Ep >> 10) << 4) | ((Ep >> 5) & 15);   // key 0..63
    const int kc = (((Ep >> 9) & 1) << 5) | (Ep & 31);     // d
    ksrc[j] = qkv + rowb + (size_t)kr * QKVN + H_ + kc;
  }
  const __bf16* vsrc;
  {
    const int e = tid * 8;
    const int ep = e ^ (((e >> 8) & 1) << 4);
    const int vd = ((ep >> 9) << 4) | ((ep >> 5) & 15);    // d
    const int vs = ep & 31;                                // s within 32-chunk
    vsrc = vbase + (size_t)vd * S_ + vs;
  }

  auto stageKV = [&](int kt, int buf) {
    load_lds16(ksrc[0] + (size_t)(kt * 64) * QKVN, &Kl[buf][tid * 8]);
    load_lds16(ksrc[1] + (size_t)(kt * 64) * QKVN, &Kl[buf][2048 + tid * 8]);
    load_lds16(vsrc + kt * 64, &Vl[buf][tid * 8]);
    load_lds16(vsrc + kt * 64 + 32, &Vl[buf][2048 + tid * 8]);
  };

  const int c0 = lane & 15, g4 = lane >> 4;
  const int swzb = (c0 * 32 + (g4 << 3)) ^ (((c0 >> 3) & 1) << 4);
  const int qt0 = z * 8 + wid * 2;   // this wave's two q-tiles
  bf16x8 qf[2][2];
#pragma unroll
  for (int qi = 0; qi < 2; ++qi) {
    const __bf16* qrow = qkv + rowb +
        (size_t)((qt0 + qi) * 16 + c0) * QKVN + (g4 << 3);
    qf[qi][0] = *(const bf16x8*)qrow;
    qf[qi][1] = *(const bf16x8*)(qrow + 32);
  }
  f32x4 oacc[2][4] = {};
  float mrow[2] = {-1e30f, -1e30f}, lsum[2] = {0.f, 0.f};

  stageKV(0, 0);
  asm volatile("s_waitcnt vmcnt(0)" ::: "memory");
  __syncthreads();   // extm + KV tile 0 ready

#pragma unroll
  for (int kt = 0; kt < 8; ++kt) {
    const int buf = kt & 1;
    if (kt + 1 < 8) stageKV(kt + 1, buf ^ 1);   // issue BEFORE compute
    bf16x8 kf[4][2], vf[2][4];
#pragma unroll
    for (int f = 0; f < 4; ++f)
#pragma unroll
      for (int half = 0; half < 2; ++half)
        kf[f][half] = *(const bf16x8*)&Kl[buf][f * 1024 + half * 512 + swzb];
#pragma unroll
    for (int ks = 0; ks < 2; ++ks)
#pragma unroll
      for (int dt = 0; dt < 4; ++dt)
        vf[ks][dt] = *(const bf16x8*)&Vl[buf][ks * 2048 + dt * 512 + swzb];
    asm volatile("s_waitcnt lgkmcnt(0)" ::: "memory");
#pragma unroll
    for (int qi = 0; qi < 2; ++qi) {
      f32x4 sc[4];
      __builtin_amdgcn_s_setprio(1);
#pragma unroll
      for (int f = 0; f < 4; ++f) {
        f32x4 z2 = {};
        z2 = mfma16(kf[f][0], qf[qi][0], z2);   // SWAPPED: C[m=key][n=q]
        z2 = mfma16(kf[f][1], qf[qi][1], z2);
#pragma unroll
        for (int r = 0; r < 4; ++r)
          sc[f][r] = z2[r] * 0.125f + extm[kt * 64 + f * 16 + (g4 << 2) + r];
      }
      __builtin_amdgcn_s_setprio(0);
      float mx = sc[0][0];
#pragma unroll
      for (int f = 0; f < 4; ++f)
#pragma unroll
        for (int r = 0; r < 4; ++r) mx = fmaxf(mx, sc[f][r]);
      mx = fmaxf(mx, __shfl_xor(mx, 16, 64));
      mx = fmaxf(mx, __shfl_xor(mx, 32, 64));
      const bool need = !__all(mx - mrow[qi] <= 8.0f);
      float al = 1.0f;
      if (need) {
        const float mn = fmaxf(mrow[qi], mx);
        al = __expf(mrow[qi] - mn);
        mrow[qi] = mn;
      }
      float rs = 0.f;
#pragma unroll
      for (int f = 0; f < 4; ++f) {
        bf16x4 pv;
#pragma unroll
        for (int r = 0; r < 4; ++r) {
          const float p = __expf(sc[f][r] - mrow[qi]);
          pv[r] = (__bf16)p;
          rs += p;
        }
        *(bf16x4*)&Pl[wid][qi][c0][f * 16 + (g4 << 2)] = pv;
      }
      rs += __shfl_xor(rs, 16, 64);
      rs += __shfl_xor(rs, 32, 64);
      lsum[qi] = lsum[qi] * al + rs;
      if (need) {
        float alr[4];
#pragma unroll
        for (int r = 0; r < 4; ++r)
          alr[r] = __shfl(al, (lane & 48) | ((g4 << 2) + r), 64);
#pragma unroll
        for (int dt = 0; dt < 4; ++dt)
#pragma unroll
          for (int r = 0; r < 4; ++r) oacc[qi][dt][r] *= alr[r];
      }
      const bf16x8 pa0 = *(const bf16x8*)&Pl[wid][qi][c0][g4 << 3];
      const bf16x8 pa1 = *(const bf16x8*)&Pl[wid][qi][c0][32 + (g4 << 3)];
      __builtin_amdgcn_s_setprio(1);
#pragma unroll
      for (int dt = 0; dt < 4; ++dt) {
        oacc[qi][dt] = mfma16(pa0, vf[0][dt], oacc[qi][dt]);
        oacc[qi][dt] = mfma16(pa1, vf[1][dt], oacc[qi][dt]);
      }
      __builtin_amdgcn_s_setprio(0);
    }
    asm volatile("s_waitcnt vmcnt(0)" ::: "memory");  // next KV tile staged
    __builtin_amdgcn_s_barrier();
  }
#pragma unroll
  for (int qi = 0; qi < 2; ++qi) {
    float inv[4];
#pragma unroll
    for (int r = 0; r < 4; ++r)
      inv[r] = 1.0f / __shfl(lsum[qi], (lane & 48) | ((g4 << 2) + r), 64);
#pragma unroll
    for (int dt = 0; dt < 4; ++dt)
#pragma unroll
      for (int r = 0; r < 4; ++r)
        ctx[(size_t)b * S_ * H_ + (size_t)h * DH_ +
            (size_t)((qt0 + qi) * 16 + (g4 << 2) + r) * H_ + dt * 16 + c0] =
            (__bf16)(oacc[qi][dt][r] * inv[r]);
  }
}

// ---------------------------------------------------------------------------
// Residual add + LayerNorm, ONE WAVE PER TOKEN. t is bf16 (half traffic).
// ---------------------------------------------------------------------------
__global__ __launch_bounds__(256) void addln_kernel(float* __restrict__ x,
                                                    const __bf16* __restrict__ t,
                                                    const float* __restrict__ g,
                                                    const float* __restrict__ bb,
                                                    __bf16* __restrict__ xb) {
  const int tok = blockIdx.x * 4 + (threadIdx.x >> 6);
  const int lane = threadIdx.x & 63;
  float* xr = x + (size_t)tok * H_;
  const __bf16* tr = t + (size_t)tok * H_;
  f32x4 v[3];
  float s = 0.f, s2 = 0.f;
#pragma unroll
  for (int i = 0; i < 3; ++i) {
    const int off = lane * 4 + i * 256;
    f32x4 a = *(const f32x4*)&xr[off];
    bf16x4 tb = *(const bf16x4*)&tr[off];
#pragma unroll
    for (int r = 0; r < 4; ++r) {
      v[i][r] = a[r] + (float)tb[r];
      s += v[i][r];
      s2 += v[i][r] * v[i][r];
    }
  }
#pragma unroll
  for (int o = 32; o > 0; o >>= 1) {
    s += __shfl_xor(s, o, 64);
    s2 += __shfl_xor(s2, o, 64);
  }
  const float mean = s * (1.0f / 768.0f);
  const float var = s2 * (1.0f / 768.0f) - mean * mean;
  const float rstd = rsqrtf(var + 1e-12f);
  __bf16* xbr = xb + (size_t)tok * H_;
#pragma unroll
  for (int i = 0; i < 3; ++i) {
    const int off = lane * 4 + i * 256;
    f32x4 gv = *(const f32x4*)&g[off];
    f32x4 bv = *(const f32x4*)&bb[off];
    f32x4 y;
    bf16x4 yb;
#pragma unroll
    for (int r = 0; r < 4; ++r) {
      y[r] = (v[i][r] - mean) * rstd * gv[r] + bv[r];
      yb[r] = (__bf16)y[r];
    }
    *(f32x4*)&xr[off] = y;
    *(bf16x4*)&xbr[off] = yb;
  }
}

// ---------------------------------------------------------------------------
// Embedding (word/star select + pos + type) + LN.
// ---------------------------------------------------------------------------
__global__ __launch_bounds__(256) void embed_kernel(
    const int* __restrict__ ids, const int* __restrict__ tt,
    const float* __restrict__ we, const float* __restrict__ se,
    const float* __restrict__ pe, const float* __restrict__ te,
    const float* __restrict__ g, const float* __restrict__ bb,
    float* __restrict__ x, __bf16* __restrict__ xb) {
  const int tok = blockIdx.x, tid = threadIdx.x;
  const int sp = tok & (S_ - 1);
  const int id = ids[tok];
  const float* e = (id >= 30700) ? se + (size_t)(id - 30700) * H_
                                 : we + (size_t)id * H_;
  const float* pr = pe + (size_t)sp * H_;
  const float* ty = te + (size_t)tt[tok] * H_;
  float v0 = e[tid] + pr[tid] + ty[tid];
  float v1 = e[tid + 256] + pr[tid + 256] + ty[tid + 256];
  float v2 = e[tid + 512] + pr[tid + 512] + ty[tid + 512];
  float s = v0 + v1 + v2;
  float s2 = v0 * v0 + v1 * v1 + v2 * v2;
  __shared__ float red1[4], red2[4];
#pragma unroll
  for (int o = 32; o > 0; o >>= 1) {
    s += __shfl_xor(s, o, 64);
    s2 += __shfl_xor(s2, o, 64);
  }
  if ((tid & 63) == 0) { red1[tid >> 6] = s; red2[tid >> 6] = s2; }
  __syncthreads();
  s = red1[0] + red1[1] + red1[2] + red1[3];
  s2 = red2[0] + red2[1] + red2[2] + red2[3];
  const float mean = s * (1.0f / 768.0f);
  const float var = s2 * (1.0f / 768.0f) - mean * mean;
  const float rstd = rsqrtf(var + 1e-12f);
  float* xr = x + (size_t)tok * H_;
  __bf16* xbr = xb + (size_t)tok * H_;
  const float y0 = (v0 - mean) * rstd * g[tid] + bb[tid];
  const float y1 = (v1 - mean) * rstd * g[tid + 256] + bb[tid + 256];
  const float y2 = (v2 - mean) * rstd * g[tid + 512] + bb[tid + 512];
  xr[tid] = y0; xr[tid + 256] = y1; xr[tid + 512] = y2;
  xbr[tid] = (__bf16)y0; xbr[tid + 256] = (__bf16)y1; xbr[tid + 512] = (__bf16)y2;
}

// ---------------------------------------------------------------------------
// Pooler: pooled[b] = tanh(x[b,0,:] @ poolW + pool_b).
// ---------------------------------------------------------------------------
__global__ __launch_bounds__(256) void pool_kernel(const float* __restrict__ x,
                                                   const __bf16* __restrict__ wT,
                                                   const float* __restrict__ pb,
                                                   float* __restrict__ out) {
  const int b = blockIdx.x, tid = threadIdx.x;
  __shared__ float xr[H_];
  for (int i = tid; i < H_; i += 256) xr[i] = x[(size_t)b * S_ * H_ + i];
  __syncthreads();
  for (int n = tid; n < H_; n += 256) {
    const __bf16* w = wT + (size_t)n * H_;
    float acc = 0.f;
    for (int k = 0; k < H_; ++k) acc += xr[k] * (float)w[k];
    out[(size_t)b * H_ + n] = tanhf(acc + pb[n]);
  }
}

// ---------------------------------------------------------------------------
extern "C" void kernel_launch(void* const* d_in, const int* in_sizes, int n_in,
                              void* d_out, int out_size, void* d_ws,
                              size_t ws_size, hipStream_t stream) {
  (void)in_sizes; (void)n_in; (void)out_size;
  const int* ids = (const int*)d_in[0];
  const int* am = (const int*)d_in[1];
  const int* tt = (const int*)d_in[2];
  const float* we = (const float*)d_in[3];
  const float* se = (const float*)d_in[4];
  const float* pe = (const float*)d_in[5];
  const float* te = (const float*)d_in[6];
  const float* eg = (const float*)d_in[7];
  const float* ebb = (const float*)d_in[8];
  const float* Wq = (const float*)d_in[9];
  const float* bq = (const float*)d_in[10];
  const float* Wk = (const float*)d_in[11];
  const float* bk = (const float*)d_in[12];
  const float* Wv = (const float*)d_in[13];
  const float* bv = (const float*)d_in[14];
  const float* Wo = (const float*)d_in[15];
  const float* bo = (const float*)d_in[16];
  const float* g1 = (const float*)d_in[17];
  const float* b1 = (const float*)d_in[18];
  const float* Wi = (const float*)d_in[19];
  const float* bi = (const float*)d_in[20];
  const float* Wf = (const float*)d_in[21];
  const float* bf_ = (const float*)d_in[22];
  const float* g2 = (const float*)d_in[23];
  const float* b2 = (const float*)d_in[24];
  const float* pw = (const float*)d_in[25];
  const float* pb = (const float*)d_in[26];

  const size_t WQKV = (size_t)L_ * QKVN * H_;
  const size_t WSQ = (size_t)L_ * H_ * H_;
  const size_t WSF = (size_t)L_ * H_ * F_;
  const size_t MN = (size_t)NTOK * H_;
  __bf16* wqkv = (__bf16*)d_ws;
  __bf16* wTo_ = wqkv + WQKV;
  __bf16* wTi_ = wTo_ + WSQ;
  __bf16* wTf_ = wTi_ + WSF;
  __bf16* wTp_ = wTf_ + WSF;
  __bf16* xb = wTp_ + (size_t)H_ * H_;
  __bf16* qkvb = xb + MN;
  __bf16* cb = qkvb + (size_t)NTOK * QKVN;
  __bf16* mid = cb + MN;
  __bf16* vtb = mid + (size_t)NTOK * F_;
  __bf16* t0b = vtb + MN;               // AO/FF2 bf16 output (12.6 MB)
  float* bqkv = (float*)(t0b + MN);
  const size_t needed = (size_t)((char*)(bqkv + (size_t)L_ * QKVN) - (char*)d_ws);
  if (ws_size < needed) return;  // insufficient scratch: visible failure

  float* x = (float*)d_out;
  float* pooled = x + MN;

  const dim3 tb(32, 8);
  const size_t zq = (size_t)QKVN * H_;
  transpose_k<<<dim3(24, 24, 12), tb, 0, stream>>>(Wq, wqkv, H_, H_, zq);
  transpose_k<<<dim3(24, 24, 12), tb, 0, stream>>>(Wk, wqkv + (size_t)H_ * H_, H_, H_, zq);
  transpose_k<<<dim3(24, 24, 12), tb, 0, stream>>>(Wv, wqkv + 2 * (size_t)H_ * H_, H_, H_, zq);
  transpose_k<<<dim3(24, 24, 12), tb, 0, stream>>>(Wo, wTo_, H_, H_, (size_t)H_ * H_);
  transpose_k<<<dim3(96, 24, 12), tb, 0, stream>>>(Wi, wTi_, H_, F_, (size_t)H_ * F_);
  transpose_k<<<dim3(24, 96, 12), tb, 0, stream>>>(Wf, wTf_, F_, H_, (size_t)H_ * F_);
  transpose_k<<<dim3(24, 24, 1), tb, 0, stream>>>(pw, wTp_, H_, H_, (size_t)H_ * H_);
  concat_bias<<<(L_ * QKVN + 255) / 256, 256, 0, stream>>>(bq, bk, bv, bqkv);

  embed_kernel<<<NTOK, 256, 0, stream>>>(ids, tt, we, se, pe, te, eg, ebb, x, xb);

  for (int l = 0; l < L_; ++l) {
    // fused QKV (V written transposed in-epilogue): 2304 blocks, Gn=18
    gemm_n64<0, 1, 1><<<(NTOK / 128) * (QKVN / 64), 256, 0, stream>>>(
        xb, wqkv + (size_t)l * QKVN * H_, bqkv + (size_t)l * QKVN,
        nullptr, qkvb, vtb, NTOK, QKVN, H_, QKVN / 64, 18);

    attn_kernel<<<NH_ * B_ * 4, 256, 0, stream>>>(qkvb, vtb, am, cb);

    // attn-out: 768 blocks, Gn=12 (B fits L2)
    gemm_n64<0, 1, 0><<<(NTOK / 128) * (H_ / 64), 256, 0, stream>>>(
        cb, wTo_ + (size_t)l * H_ * H_, bo + l * H_, nullptr, t0b, nullptr,
        NTOK, H_, H_, H_ / 64, 12);
    addln_kernel<<<NTOK / 4, 256, 0, stream>>>(x, t0b, g1 + l * H_, b1 + l * H_, xb);

    // FF1: 3072 blocks, Gn=24 (B group 2.35MB, L2-resident)
    gemm_n64<1, 1, 0><<<(NTOK / 128) * (F_ / 64), 256, 0, stream>>>(
        xb, wTi_ + (size_t)l * H_ * F_, bi + l * F_, nullptr, mid, nullptr,
        NTOK, F_, H_, F_ / 64, 24);
    // FF2: 768 blocks, Gn=6 (K=3072: B group 2.35MB)
    gemm_n64<0, 1, 0><<<(NTOK / 128) * (H_ / 64), 256, 0, stream>>>(
        mid, wTf_ + (size_t)l * F_ * H_, bf_ + l * H_, nullptr, t0b, nullptr,
        NTOK, H_, F_, H_ / 64, 6);
    addln_kernel<<<NTOK / 4, 256, 0, stream>>>(x, t0b, g2 + l * H_, b2 + l * H_, xb);
  }

  pool_kernel<<<B_, 256, 0, stream>>>(x, wTp_, pb, pooled);
}

// Round 23
// 2838.093 us; speedup vs baseline: 1.0911x; 1.0059x over previous
//
#include <hip/hip_runtime.h>
#include <hip/hip_bf16.h>
#include <math.h>

// ---------------------------------------------------------------------------
// KVPLM Star Encoder: 12 layers, H=768, NH=12, F=3072, B=16, S=512.
// Round 23: FF2 Gn 6 -> 12 (single group; avoids doubling the 50MB A read —
// per-XCD working set 11MB vs 15MB). QKV 18 / AO 12 / FF1 24 keep R22's
// proven grouped raster. Everything else frozen at R22.
// ---------------------------------------------------------------------------

#define L_   12
#define H_   768
#define NH_  12
#define DH_  64
#define F_   3072
#define B_   16
#define S_   512
#define NTOK (B_ * S_)   // 8192
#define QKVN 2304

typedef __attribute__((ext_vector_type(8))) __bf16 bf16x8;
typedef __attribute__((ext_vector_type(4))) __bf16 bf16x4;
typedef __attribute__((ext_vector_type(4))) float  f32x4;

static __device__ __forceinline__ f32x4 mfma16(bf16x8 a, bf16x8 b, f32x4 c) {
  return __builtin_amdgcn_mfma_f32_16x16x32_bf16(a, b, c, 0, 0, 0);
}

static __device__ __forceinline__ void load_lds16(const void* g, void* l) {
  __builtin_amdgcn_global_load_lds(
      (const __attribute__((address_space(1))) void*)g,
      (__attribute__((address_space(3))) void*)l, 16, 0, 0);
}

// tanh-approx GELU (max dev vs exact ~4e-4, under bf16 rounding)
static __device__ __forceinline__ float gelu_fast(float v) {
  const float u = 1.5957691216057308f * v * (1.0f + 0.044715f * v * v);
  return v / (1.0f + __expf(-u));
}

// ---------------------------------------------------------------------------
// Weight transpose+convert: in fp32 [Z][R][C] -> out bf16 [Z (stride outZ)][C][R]
// ---------------------------------------------------------------------------
__global__ __launch_bounds__(256) void transpose_k(const float* __restrict__ in,
                                                   __bf16* __restrict__ out,
                                                   int R, int C, size_t outZ) {
  __shared__ float t[32][33];
  const int z = blockIdx.z;
  const float* inz = in + (size_t)z * R * C;
  __bf16* outz = out + (size_t)z * outZ;
  const int c0 = blockIdx.x * 32, r0 = blockIdx.y * 32;
  const int tx = threadIdx.x, ty = threadIdx.y;
#pragma unroll
  for (int i = 0; i < 32; i += 8)
    t[ty + i][tx] = inz[(size_t)(r0 + ty + i) * C + c0 + tx];
  __syncthreads();
#pragma unroll
  for (int i = 0; i < 32; i += 8)
    outz[(size_t)(c0 + ty + i) * R + r0 + tx] = (__bf16)t[tx][ty + i];
}

__global__ __launch_bounds__(256) void concat_bias(const float* __restrict__ bq,
                                                   const float* __restrict__ bk,
                                                   const float* __restrict__ bv,
                                                   float* __restrict__ o) {
  const int i = blockIdx.x * 256 + threadIdx.x;
  if (i >= L_ * QKVN) return;
  const int l = i / QKVN, j = i - l * QKVN;
  float v;
  if (j < H_) v = bq[l * H_ + j];
  else if (j < 2 * H_) v = bk[l * H_ + j - H_];
  else v = bv[l * H_ + j - 2 * H_];
  o[i] = v;
}

// ---------------------------------------------------------------------------
// gemm_n64: 2-phase 128x64 GEMM, BK=64, LDS 48 KiB dbuf -> 3 blocks/CU.
// T2 st_16x32 swizzle + T3-minimal schedule. Grouped-N raster (Gn N-tiles
// per group); order (group, M, n-in-group). VT=1 (QKV): cols >= 2H write
// transposed into vtp (bf16x4 per frag).
// ---------------------------------------------------------------------------
template <int EPI, int OUTBF, int VT>
__global__ __launch_bounds__(256, 3) void gemm_n64(const __bf16* __restrict__ A,
                                                   const __bf16* __restrict__ Bt,
                                                   const float* __restrict__ bias,
                                                   float* __restrict__ Cf,
                                                   __bf16* __restrict__ Cb,
                                                   __bf16* __restrict__ vtp,
                                                   int M, int N, int K,
                                                   int Ntiles, int Gn) {
  alignas(16) __shared__ __bf16 lds[24576];  // [buf2][A 8192 | B 4096] el
  const int tid = threadIdx.x, wid = tid >> 6, lane = tid & 63;
  int bid = blockIdx.x;
  const int nwg = gridDim.x;
  if ((nwg & 7) == 0) bid = (bid & 7) * (nwg >> 3) + (bid >> 3);  // XCD swizzle
  // grouped-N raster: (group, M, n-within-group)
  const int Mtiles = M >> 7;
  const int gsz = Mtiles * Gn;
  const int grp = bid / gsz;
  const int within = bid - grp * gsz;
  const int bm = (within / Gn) << 7;
  const int bn = (grp * Gn + (within % Gn)) << 6;
  const int nt = K >> 6;

  const __bf16* pA[4];
  const __bf16* pB[2];
#pragma unroll
  for (int j = 0; j < 4; ++j) {
    const int E = (j << 11) + tid * 8;
    const int Ep = E ^ (((E >> 8) & 1) << 4);
    const int r = ((Ep >> 10) << 4) | ((Ep >> 5) & 15);
    const int c = (((Ep >> 9) & 1) << 5) | (Ep & 31);
    pA[j] = A + (size_t)(bm + r) * K + c;
    if (j < 2) pB[j] = Bt + (size_t)(bn + r) * K + c;  // r < 64 for E < 4096
  }

  auto stage = [&](int t, int buf) {
    __bf16* base = &lds[buf * 12288 + (wid << 9)];
    const size_t off = (size_t)(t << 6);
#pragma unroll
    for (int j = 0; j < 4; ++j) load_lds16(pA[j] + off, base + (j << 11));
#pragma unroll
    for (int j = 0; j < 2; ++j) load_lds16(pB[j] + off, base + 8192 + (j << 11));
  };

  const int frow = lane & 15, fk = (lane >> 4) << 3;
  const int swzb = (frow * 32 + fk) ^ (((frow >> 3) & 1) << 4);
  const int mh = wid >> 1, nq = wid & 1;  // wave tile 64x32

  f32x4 acc[4][2] = {};

  stage(0, 0);
  asm volatile("s_waitcnt vmcnt(0)" ::: "memory");
  __builtin_amdgcn_s_barrier();

  for (int t = 0; t < nt; ++t) {
    const int buf = t & 1;
    if (t + 1 < nt) stage(t + 1, buf ^ 1);   // issue BEFORE ds_read+MFMA
    const __bf16* LA = &lds[buf * 12288 + (mh << 12)];
    const __bf16* LB = &lds[buf * 12288 + 8192 + (nq << 11)];
    bf16x8 a[4][2], b[2][2];
#pragma unroll
    for (int mi = 0; mi < 4; ++mi)
#pragma unroll
      for (int ks = 0; ks < 2; ++ks)
        a[mi][ks] = *(const bf16x8*)&LA[mi * 1024 + ks * 512 + swzb];
#pragma unroll
    for (int ni = 0; ni < 2; ++ni)
#pragma unroll
      for (int ks = 0; ks < 2; ++ks)
        b[ni][ks] = *(const bf16x8*)&LB[ni * 1024 + ks * 512 + swzb];
    asm volatile("s_waitcnt lgkmcnt(0)" ::: "memory");
    __builtin_amdgcn_s_setprio(1);
#pragma unroll
    for (int mi = 0; mi < 4; ++mi)
#pragma unroll
      for (int ni = 0; ni < 2; ++ni)
#pragma unroll
        for (int ks = 0; ks < 2; ++ks)
          acc[mi][ni] = mfma16(a[mi][ks], b[ni][ks], acc[mi][ni]);
    __builtin_amdgcn_s_setprio(0);
    asm volatile("s_waitcnt vmcnt(0)" ::: "memory");  // next tile staged
    __builtin_amdgcn_s_barrier();
  }

  // epilogue: C/D layout col=lane&15, row=(lane>>4)*4+r  [m89 verified]
  const int r0 = (lane >> 4) << 2, c0 = lane & 15;
  const int wrow = bm + (mh << 6), wcol = bn + (nq << 5);
#pragma unroll
  for (int ni = 0; ni < 2; ++ni) {
    const int col = wcol + (ni << 4) + c0;
    const float bv = bias[col];
    if (VT && (wcol + (ni << 4)) >= 2 * H_) {
      const int hh = (col - 2 * H_) >> 6, dd = (col - 2 * H_) & 63;
#pragma unroll
      for (int mi = 0; mi < 4; ++mi) {
        const int row = wrow + (mi << 4) + r0;
        bf16x4 pv;
#pragma unroll
        for (int r = 0; r < 4; ++r) pv[r] = (__bf16)(acc[mi][ni][r] + bv);
        const int bb2 = row >> 9, ss = row & 511;
        *(bf16x4*)&vtp[((size_t)(bb2 * NH_ + hh) * DH_ + dd) * S_ + ss] = pv;
      }
    } else {
#pragma unroll
      for (int mi = 0; mi < 4; ++mi) {
        const int row = wrow + (mi << 4) + r0;
#pragma unroll
        for (int r = 0; r < 4; ++r) {
          float v = acc[mi][ni][r] + bv;
          if (EPI == 1) v = gelu_fast(v);
          if (OUTBF)
            Cb[(size_t)(row + r) * N + col] = (__bf16)v;
          else
            Cf[(size_t)(row + r) * N + col] = v;
        }
      }
    }
  }
}

// ---------------------------------------------------------------------------
// Flash attention, swapped QK^T, TWO q-tiles/wave, 64-KEY KV tiles (8 iters),
// T13 defer-max. LDS 52 KB -> 3 blocks/CU. Grid 768 linear, XCD-chunked.
// ---------------------------------------------------------------------------
__global__ __launch_bounds__(256, 3) void attn_kernel(const __bf16* __restrict__ qkv,
                                                      const __bf16* __restrict__ vt,
                                                      const int* __restrict__ amask,
                                                      __bf16* __restrict__ ctx) {
  __shared__ float extm[S_];                      // 2 KB
  alignas(16) __shared__ __bf16 Kl[2][4096];      // 16 KB
  alignas(16) __shared__ __bf16 Vl[2][4096];      // 16 KB
  __shared__ __bf16 Pl[4][2][16][72];             // 18 KB (pad 64->72)
  const int swz = ((int)blockIdx.x & 7) * 96 + ((int)blockIdx.x >> 3);
  const int z = swz & 3;
  const int hb = swz >> 2;
  const int h = hb % NH_, b = hb / NH_;
  const int tid = threadIdx.x, wid = tid >> 6, lane = tid & 63;
  const size_t rowb = (size_t)b * S_ * QKVN + (size_t)h * DH_;
  const __bf16* vbase = vt + ((size_t)(b * NH_ + h) * DH_) * S_;

  for (int i = tid; i < S_; i += 256)
    extm[i] = (1.0f - (float)amask[b * S_ + i]) * -10000.0f;

  const __bf16* ksrc[2];
#pragma unroll
  for (int j = 0; j < 2; ++j) {
    const int E = (j << 11) + tid * 8;
    const int Ep = E ^ (((E >> 8) & 1) << 4);
    const int kr = ((Ep >> 10) << 4) | ((Ep >> 5) & 15);   // key 0..63
    const int kc = (((Ep >> 9) & 1) << 5) | (Ep & 31);     // d
    ksrc[j] = qkv + rowb + (size_t)kr * QKVN + H_ + kc;
  }
  const __bf16* vsrc;
  {
    const int e = tid * 8;
    const int ep = e ^ (((e >> 8) & 1) << 4);
    const int vd = ((ep >> 9) << 4) | ((ep >> 5) & 15);    // d
    const int vs = ep & 31;                                // s within 32-chunk
    vsrc = vbase + (size_t)vd * S_ + vs;
  }

  auto stageKV = [&](int kt, int buf) {
    load_lds16(ksrc[0] + (size_t)(kt * 64) * QKVN, &Kl[buf][tid * 8]);
    load_lds16(ksrc[1] + (size_t)(kt * 64) * QKVN, &Kl[buf][2048 + tid * 8]);
    load_lds16(vsrc + kt * 64, &Vl[buf][tid * 8]);
    load_lds16(vsrc + kt * 64 + 32, &Vl[buf][2048 + tid * 8]);
  };

  const int c0 = lane & 15, g4 = lane >> 4;
  const int swzb = (c0 * 32 + (g4 << 3)) ^ (((c0 >> 3) & 1) << 4);
  const int qt0 = z * 8 + wid * 2;   // this wave's two q-tiles
  bf16x8 qf[2][2];
#pragma unroll
  for (int qi = 0; qi < 2; ++qi) {
    const __bf16* qrow = qkv + rowb +
        (size_t)((qt0 + qi) * 16 + c0) * QKVN + (g4 << 3);
    qf[qi][0] = *(const bf16x8*)qrow;
    qf[qi][1] = *(const bf16x8*)(qrow + 32);
  }
  f32x4 oacc[2][4] = {};
  float mrow[2] = {-1e30f, -1e30f}, lsum[2] = {0.f, 0.f};

  stageKV(0, 0);
  asm volatile("s_waitcnt vmcnt(0)" ::: "memory");
  __syncthreads();   // extm + KV tile 0 ready

#pragma unroll
  for (int kt = 0; kt < 8; ++kt) {
    const int buf = kt & 1;
    if (kt + 1 < 8) stageKV(kt + 1, buf ^ 1);   // issue BEFORE compute
    bf16x8 kf[4][2], vf[2][4];
#pragma unroll
    for (int f = 0; f < 4; ++f)
#pragma unroll
      for (int half = 0; half < 2; ++half)
        kf[f][half] = *(const bf16x8*)&Kl[buf][f * 1024 + half * 512 + swzb];
#pragma unroll
    for (int ks = 0; ks < 2; ++ks)
#pragma unroll
      for (int dt = 0; dt < 4; ++dt)
        vf[ks][dt] = *(const bf16x8*)&Vl[buf][ks * 2048 + dt * 512 + swzb];
    asm volatile("s_waitcnt lgkmcnt(0)" ::: "memory");
#pragma unroll
    for (int qi = 0; qi < 2; ++qi) {
      f32x4 sc[4];
      __builtin_amdgcn_s_setprio(1);
#pragma unroll
      for (int f = 0; f < 4; ++f) {
        f32x4 z2 = {};
        z2 = mfma16(kf[f][0], qf[qi][0], z2);   // SWAPPED: C[m=key][n=q]
        z2 = mfma16(kf[f][1], qf[qi][1], z2);
#pragma unroll
        for (int r = 0; r < 4; ++r)
          sc[f][r] = z2[r] * 0.125f + extm[kt * 64 + f * 16 + (g4 << 2) + r];
      }
      __builtin_amdgcn_s_setprio(0);
      float mx = sc[0][0];
#pragma unroll
      for (int f = 0; f < 4; ++f)
#pragma unroll
        for (int r = 0; r < 4; ++r) mx = fmaxf(mx, sc[f][r]);
      mx = fmaxf(mx, __shfl_xor(mx, 16, 64));
      mx = fmaxf(mx, __shfl_xor(mx, 32, 64));
      const bool need = !__all(mx - mrow[qi] <= 8.0f);
      float al = 1.0f;
      if (need) {
        const float mn = fmaxf(mrow[qi], mx);
        al = __expf(mrow[qi] - mn);
        mrow[qi] = mn;
      }
      float rs = 0.f;
#pragma unroll
      for (int f = 0; f < 4; ++f) {
        bf16x4 pv;
#pragma unroll
        for (int r = 0; r < 4; ++r) {
          const float p = __expf(sc[f][r] - mrow[qi]);
          pv[r] = (__bf16)p;
          rs += p;
        }
        *(bf16x4*)&Pl[wid][qi][c0][f * 16 + (g4 << 2)] = pv;
      }
      rs += __shfl_xor(rs, 16, 64);
      rs += __shfl_xor(rs, 32, 64);
      lsum[qi] = lsum[qi] * al + rs;
      if (need) {
        float alr[4];
#pragma unroll
        for (int r = 0; r < 4; ++r)
          alr[r] = __shfl(al, (lane & 48) | ((g4 << 2) + r), 64);
#pragma unroll
        for (int dt = 0; dt < 4; ++dt)
#pragma unroll
          for (int r = 0; r < 4; ++r) oacc[qi][dt][r] *= alr[r];
      }
      const bf16x8 pa0 = *(const bf16x8*)&Pl[wid][qi][c0][g4 << 3];
      const bf16x8 pa1 = *(const bf16x8*)&Pl[wid][qi][c0][32 + (g4 << 3)];
      __builtin_amdgcn_s_setprio(1);
#pragma unroll
      for (int dt = 0; dt < 4; ++dt) {
        oacc[qi][dt] = mfma16(pa0, vf[0][dt], oacc[qi][dt]);
        oacc[qi][dt] = mfma16(pa1, vf[1][dt], oacc[qi][dt]);
      }
      __builtin_amdgcn_s_setprio(0);
    }
    asm volatile("s_waitcnt vmcnt(0)" ::: "memory");  // next KV tile staged
    __builtin_amdgcn_s_barrier();
  }
#pragma unroll
  for (int qi = 0; qi < 2; ++qi) {
    float inv[4];
#pragma unroll
    for (int r = 0; r < 4; ++r)
      inv[r] = 1.0f / __shfl(lsum[qi], (lane & 48) | ((g4 << 2) + r), 64);
#pragma unroll
    for (int dt = 0; dt < 4; ++dt)
#pragma unroll
      for (int r = 0; r < 4; ++r)
        ctx[(size_t)b * S_ * H_ + (size_t)h * DH_ +
            (size_t)((qt0 + qi) * 16 + (g4 << 2) + r) * H_ + dt * 16 + c0] =
            (__bf16)(oacc[qi][dt][r] * inv[r]);
  }
}

// ---------------------------------------------------------------------------
// Residual add + LayerNorm, ONE WAVE PER TOKEN. t is bf16 (half traffic).
// ---------------------------------------------------------------------------
__global__ __launch_bounds__(256) void addln_kernel(float* __restrict__ x,
                                                    const __bf16* __restrict__ t,
                                                    const float* __restrict__ g,
                                                    const float* __restrict__ bb,
                                                    __bf16* __restrict__ xb) {
  const int tok = blockIdx.x * 4 + (threadIdx.x >> 6);
  const int lane = threadIdx.x & 63;
  float* xr = x + (size_t)tok * H_;
  const __bf16* tr = t + (size_t)tok * H_;
  f32x4 v[3];
  float s = 0.f, s2 = 0.f;
#pragma unroll
  for (int i = 0; i < 3; ++i) {
    const int off = lane * 4 + i * 256;
    f32x4 a = *(const f32x4*)&xr[off];
    bf16x4 tb = *(const bf16x4*)&tr[off];
#pragma unroll
    for (int r = 0; r < 4; ++r) {
      v[i][r] = a[r] + (float)tb[r];
      s += v[i][r];
      s2 += v[i][r] * v[i][r];
    }
  }
#pragma unroll
  for (int o = 32; o > 0; o >>= 1) {
    s += __shfl_xor(s, o, 64);
    s2 += __shfl_xor(s2, o, 64);
  }
  const float mean = s * (1.0f / 768.0f);
  const float var = s2 * (1.0f / 768.0f) - mean * mean;
  const float rstd = rsqrtf(var + 1e-12f);
  __bf16* xbr = xb + (size_t)tok * H_;
#pragma unroll
  for (int i = 0; i < 3; ++i) {
    const int off = lane * 4 + i * 256;
    f32x4 gv = *(const f32x4*)&g[off];
    f32x4 bv = *(const f32x4*)&bb[off];
    f32x4 y;
    bf16x4 yb;
#pragma unroll
    for (int r = 0; r < 4; ++r) {
      y[r] = (v[i][r] - mean) * rstd * gv[r] + bv[r];
      yb[r] = (__bf16)y[r];
    }
    *(f32x4*)&xr[off] = y;
    *(bf16x4*)&xbr[off] = yb;
  }
}

// ---------------------------------------------------------------------------
// Embedding (word/star select + pos + type) + LN.
// ---------------------------------------------------------------------------
__global__ __launch_bounds__(256) void embed_kernel(
    const int* __restrict__ ids, const int* __restrict__ tt,
    const float* __restrict__ we, const float* __restrict__ se,
    const float* __restrict__ pe, const float* __restrict__ te,
    const float* __restrict__ g, const float* __restrict__ bb,
    float* __restrict__ x, __bf16* __restrict__ xb) {
  const int tok = blockIdx.x, tid = threadIdx.x;
  const int sp = tok & (S_ - 1);
  const int id = ids[tok];
  const float* e = (id >= 30700) ? se + (size_t)(id - 30700) * H_
                                 : we + (size_t)id * H_;
  const float* pr = pe + (size_t)sp * H_;
  const float* ty = te + (size_t)tt[tok] * H_;
  float v0 = e[tid] + pr[tid] + ty[tid];
  float v1 = e[tid + 256] + pr[tid + 256] + ty[tid + 256];
  float v2 = e[tid + 512] + pr[tid + 512] + ty[tid + 512];
  float s = v0 + v1 + v2;
  float s2 = v0 * v0 + v1 * v1 + v2 * v2;
  __shared__ float red1[4], red2[4];
#pragma unroll
  for (int o = 32; o > 0; o >>= 1) {
    s += __shfl_xor(s, o, 64);
    s2 += __shfl_xor(s2, o, 64);
  }
  if ((tid & 63) == 0) { red1[tid >> 6] = s; red2[tid >> 6] = s2; }
  __syncthreads();
  s = red1[0] + red1[1] + red1[2] + red1[3];
  s2 = red2[0] + red2[1] + red2[2] + red2[3];
  const float mean = s * (1.0f / 768.0f);
  const float var = s2 * (1.0f / 768.0f) - mean * mean;
  const float rstd = rsqrtf(var + 1e-12f);
  float* xr = x + (size_t)tok * H_;
  __bf16* xbr = xb + (size_t)tok * H_;
  const float y0 = (v0 - mean) * rstd * g[tid] + bb[tid];
  const float y1 = (v1 - mean) * rstd * g[tid + 256] + bb[tid + 256];
  const float y2 = (v2 - mean) * rstd * g[tid + 512] + bb[tid + 512];
  xr[tid] = y0; xr[tid + 256] = y1; xr[tid + 512] = y2;
  xbr[tid] = (__bf16)y0; xbr[tid + 256] = (__bf16)y1; xbr[tid + 512] = (__bf16)y2;
}

// ---------------------------------------------------------------------------
// Pooler: pooled[b] = tanh(x[b,0,:] @ poolW + pool_b).
// ---------------------------------------------------------------------------
__global__ __launch_bounds__(256) void pool_kernel(const float* __restrict__ x,
                                                   const __bf16* __restrict__ wT,
                                                   const float* __restrict__ pb,
                                                   float* __restrict__ out) {
  const int b = blockIdx.x, tid = threadIdx.x;
  __shared__ float xr[H_];
  for (int i = tid; i < H_; i += 256) xr[i] = x[(size_t)b * S_ * H_ + i];
  __syncthreads();
  for (int n = tid; n < H_; n += 256) {
    const __bf16* w = wT + (size_t)n * H_;
    float acc = 0.f;
    for (int k = 0; k < H_; ++k) acc += xr[k] * (float)w[k];
    out[(size_t)b * H_ + n] = tanhf(acc + pb[n]);
  }
}

// ---------------------------------------------------------------------------
extern "C" void kernel_launch(void* const* d_in, const int* in_sizes, int n_in,
                              void* d_out, int out_size, void* d_ws,
                              size_t ws_size, hipStream_t stream) {
  (void)in_sizes; (void)n_in; (void)out_size;
  const int* ids = (const int*)d_in[0];
  const int* am = (const int*)d_in[1];
  const int* tt = (const int*)d_in[2];
  const float* we = (const float*)d_in[3];
  const float* se = (const float*)d_in[4];
  const float* pe = (const float*)d_in[5];
  const float* te = (const float*)d_in[6];
  const float* eg = (const float*)d_in[7];
  const float* ebb = (const float*)d_in[8];
  const float* Wq = (const float*)d_in[9];
  const float* bq = (const float*)d_in[10];
  const float* Wk = (const float*)d_in[11];
  const float* bk = (const float*)d_in[12];
  const float* Wv = (const float*)d_in[13];
  const float* bv = (const float*)d_in[14];
  const float* Wo = (const float*)d_in[15];
  const float* bo = (const float*)d_in[16];
  const float* g1 = (const float*)d_in[17];
  const float* b1 = (const float*)d_in[18];
  const float* Wi = (const float*)d_in[19];
  const float* bi = (const float*)d_in[20];
  const float* Wf = (const float*)d_in[21];
  const float* bf_ = (const float*)d_in[22];
  const float* g2 = (const float*)d_in[23];
  const float* b2 = (const float*)d_in[24];
  const float* pw = (const float*)d_in[25];
  const float* pb = (const float*)d_in[26];

  const size_t WQKV = (size_t)L_ * QKVN * H_;
  const size_t WSQ = (size_t)L_ * H_ * H_;
  const size_t WSF = (size_t)L_ * H_ * F_;
  const size_t MN = (size_t)NTOK * H_;
  __bf16* wqkv = (__bf16*)d_ws;
  __bf16* wTo_ = wqkv + WQKV;
  __bf16* wTi_ = wTo_ + WSQ;
  __bf16* wTf_ = wTi_ + WSF;
  __bf16* wTp_ = wTf_ + WSF;
  __bf16* xb = wTp_ + (size_t)H_ * H_;
  __bf16* qkvb = xb + MN;
  __bf16* cb = qkvb + (size_t)NTOK * QKVN;
  __bf16* mid = cb + MN;
  __bf16* vtb = mid + (size_t)NTOK * F_;
  __bf16* t0b = vtb + MN;               // AO/FF2 bf16 output (12.6 MB)
  float* bqkv = (float*)(t0b + MN);
  const size_t needed = (size_t)((char*)(bqkv + (size_t)L_ * QKVN) - (char*)d_ws);
  if (ws_size < needed) return;  // insufficient scratch: visible failure

  float* x = (float*)d_out;
  float* pooled = x + MN;

  const dim3 tb(32, 8);
  const size_t zq = (size_t)QKVN * H_;
  transpose_k<<<dim3(24, 24, 12), tb, 0, stream>>>(Wq, wqkv, H_, H_, zq);
  transpose_k<<<dim3(24, 24, 12), tb, 0, stream>>>(Wk, wqkv + (size_t)H_ * H_, H_, H_, zq);
  transpose_k<<<dim3(24, 24, 12), tb, 0, stream>>>(Wv, wqkv + 2 * (size_t)H_ * H_, H_, H_, zq);
  transpose_k<<<dim3(24, 24, 12), tb, 0, stream>>>(Wo, wTo_, H_, H_, (size_t)H_ * H_);
  transpose_k<<<dim3(96, 24, 12), tb, 0, stream>>>(Wi, wTi_, H_, F_, (size_t)H_ * F_);
  transpose_k<<<dim3(24, 96, 12), tb, 0, stream>>>(Wf, wTf_, F_, H_, (size_t)H_ * F_);
  transpose_k<<<dim3(24, 24, 1), tb, 0, stream>>>(pw, wTp_, H_, H_, (size_t)H_ * H_);
  concat_bias<<<(L_ * QKVN + 255) / 256, 256, 0, stream>>>(bq, bk, bv, bqkv);

  embed_kernel<<<NTOK, 256, 0, stream>>>(ids, tt, we, se, pe, te, eg, ebb, x, xb);

  for (int l = 0; l < L_; ++l) {
    // fused QKV (V written transposed in-epilogue): 2304 blocks, Gn=18
    gemm_n64<0, 1, 1><<<(NTOK / 128) * (QKVN / 64), 256, 0, stream>>>(
        xb, wqkv + (size_t)l * QKVN * H_, bqkv + (size_t)l * QKVN,
        nullptr, qkvb, vtb, NTOK, QKVN, H_, QKVN / 64, 18);

    attn_kernel<<<NH_ * B_ * 4, 256, 0, stream>>>(qkvb, vtb, am, cb);

    // attn-out: 768 blocks, Gn=12 (single group)
    gemm_n64<0, 1, 0><<<(NTOK / 128) * (H_ / 64), 256, 0, stream>>>(
        cb, wTo_ + (size_t)l * H_ * H_, bo + l * H_, nullptr, t0b, nullptr,
        NTOK, H_, H_, H_ / 64, 12);
    addln_kernel<<<NTOK / 4, 256, 0, stream>>>(x, t0b, g1 + l * H_, b1 + l * H_, xb);

    // FF1: 3072 blocks, Gn=24 (B group 2.35MB, L2-resident)
    gemm_n64<1, 1, 0><<<(NTOK / 128) * (F_ / 64), 256, 0, stream>>>(
        xb, wTi_ + (size_t)l * H_ * F_, bi + l * F_, nullptr, mid, nullptr,
        NTOK, F_, H_, F_ / 64, 24);
    // FF2: 768 blocks, Gn=12 (single group; A read once — 50MB mid dominates)
    gemm_n64<0, 1, 0><<<(NTOK / 128) * (H_ / 64), 256, 0, stream>>>(
        mid, wTf_ + (size_t)l * F_ * H_, bf_ + l * H_, nullptr, t0b, nullptr,
        NTOK, H_, F_, H_ / 64, 12);
    addln_kernel<<<NTOK / 4, 256, 0, stream>>>(x, t0b, g2 + l * H_, b2 + l * H_, xb);
  }

  pool_kernel<<<B_, 256, 0, stream>>>(x, wTp_, pb, pooled);
}